// Round 9
// baseline (830.528 us; speedup 1.0000x reference)
//
#include <hip/hip_runtime.h>
#include <cstdint>
#include <cstddef>

typedef unsigned long long u64;
typedef uint32_t u32;
typedef uint16_t u16;
typedef uint8_t u8;

// ---------------------------------------------------------------------------
// Binary AlexNet-1D. bq(w)=0.1*sign(w), bact(x)=sign(x). All binary layers are
// exact integer XNOR-popcount + f64 affine epilogue. Activations bitpacked as
// [N][L][C/64] u64. Conv sum = CIN*K - 2*popc(a^w); maxpool (stride==kernel,
// scale 0.1>0) commutes with the affine map, so pool the integer sums.
// Layer 1 (real f32 input): lane = output channel; per-lane +-1.0f weights in
// VGPRs; x is wave-uniform -> SGPR via s_load (readfirstlane'd base + const
// offsets). Inner loop = pure v_fmac. 10 conv positions (2 pool windows) per
// iteration, 8 iterations per block. Near-zero outputs (|v| < margin) are
// recomputed in f64 by a fixup kernel -> sign decisions stay f64-exact.
// Layers 4..6 + fc1 + fc2 fused into one block-per-sample kernel (LDS).
// ---------------------------------------------------------------------------

#define CONV1_MARGIN 1e-4f

// -------------------- merged weight packing --------------------
// packs w[Cout][CIN][K] float -> wpk[K][Cout][CIN/64]; fc layers use K=1.
struct PackJob { const float* src; u64* dst; int Cout, CIN, K, waveBase; };
struct PackJobs { PackJob j[6]; int totalWaves; };

__global__ void pack_all_kernel(PackJobs P)
{
    int gtid = blockIdx.x * blockDim.x + threadIdx.x;
    int wid = gtid >> 6, lane = gtid & 63;
    if (wid >= P.totalWaves) return;
    int jj = 0;
    #pragma unroll
    for (int i = 1; i < 6; ++i) if (wid >= P.j[i].waveBase) jj = i;
    PackJob job = P.j[jj];
    int lw = wid - job.waveBase;
    int W = job.CIN >> 6;
    int wg = lw % W;
    int co = (lw / W) % job.Cout;
    int k  = lw / (W * job.Cout);
    int ci = wg * 64 + lane;
    bool sg = job.src[((size_t)co * job.CIN + ci) * job.K + k] >= 0.0f;
    u64 word = __ballot(sg);
    if (lane == 0) job.dst[lw] = word;
}

// fc1 weights: fw1[512][32] -> u32[512] sign bitmask (bit i = input i)
__global__ void packfc1_kernel(const float* __restrict__ fw1, u32* __restrict__ fw1pk)
{
    int o = blockIdx.x * blockDim.x + threadIdx.x;
    if (o >= 512) return;
    u32 wd = 0;
    #pragma unroll
    for (int i = 0; i < 32; ++i) wd |= (u32)(fw1[o * 32 + i] >= 0.0f) << i;
    fw1pk[o] = wd;
}

// layer-1 weight signs as f32 +-1.0: sgnf[i][co]  ([69][256])
__global__ void pack_sgn1_kernel(const float* __restrict__ w1, float* __restrict__ sgnf)
{
    int idx = blockIdx.x * blockDim.x + threadIdx.x;
    if (idx >= 256 * 69) return;
    int co = idx / 69, i = idx % 69;
    sgnf[i * 256 + co] = (w1[(size_t)co * 69 + i] >= 0.0f) ? 1.0f : -1.0f;
}

// stage x into padded ws copy: [16 zero][128*3*2560 data][16 zero]
__global__ void padx_kernel(const float* __restrict__ x, float* __restrict__ wsx)
{
    const int total = 128 * 3 * 2560;
    int i = blockIdx.x * blockDim.x + threadIdx.x;
    if (i < 16) { wsx[i] = 0.0f; wsx[16 + total + i] = 0.0f; }
    if (i < total) wsx[16 + i] = x[i];
}

// -------------------- layer 1 --------------------
// grid (n=128, by=31), block 256 (tid = co). Each iteration handles one
// position block: 10 conv positions = pool windows lp = 2*pb, 2*pb+1.
// Weights w[69] per-lane VGPR (+-1.0f); x via wave-uniform s_load.
__global__ __launch_bounds__(256, 1) void conv1_pass1_kernel(
    const float* __restrict__ wsx,   // padded x
    const float* __restrict__ sgnf,  // [69][256] +-1.0f
    const float* __restrict__ b, const float* __restrict__ sw,
    const float* __restrict__ sb,
    u64* __restrict__ opk64, u64* __restrict__ uflag64)
{
    const int Lconv = 2406;
    int n = blockIdx.x, by = blockIdx.y;
    int tid = threadIdx.x;           // == co
    int lane = tid & 63, wv = tid >> 6;
    int co = tid;

    float w[69];
    #pragma unroll
    for (int i = 0; i < 69; ++i) w[i] = sgnf[i * 256 + co];
    float bc = b[co];
    float swc = (sw[co] >= 0.0f) ? 0.1f : -0.1f;
    float sbc = sb[co];

    const float* xs = wsx + 16 + (size_t)n * 7680;   // sample base (padded +-16)

    for (int it = 0; it < 8; ++it) {
        int pb = by * 8 + it;
        if (pb >= 241) break;                         // uniform
        int l0 = 10 * pb - 2;
        int ub = __builtin_amdgcn_readfirstlane(l0);  // SGPR base offset

        float acc[10];
        #pragma unroll
        for (int j = 0; j < 10; ++j) acc[j] = 0.0f;

        #pragma unroll
        for (int ci = 0; ci < 3; ++ci) {
            #pragma unroll
            for (int kk = 0; kk < 23; ++kk) {
                float wv_ = w[ci * 23 + kk];
                #pragma unroll
                for (int j = 0; j < 10; ++j) {
                    float xv = xs[ub + ci * 2560 + 7 * kk + j];  // s_load (uniform)
                    acc[j] = fmaf(xv, wv_, acc[j]);
                }
            }
        }

        #pragma unroll
        for (int wi = 0; wi < 2; ++wi) {
            int lp = 2 * pb + wi;
            float best = -1e30f;
            #pragma unroll
            for (int j = 0; j < 5; ++j) {
                int l = l0 + wi * 5 + j;              // uniform bounds
                if (l >= 0 && l < Lconv) best = fmaxf(best, acc[wi * 5 + j]);
            }
            float v = swc * (0.1f * best + bc) + sbc;
            u64 wb = __ballot(v >= 0.0f);
            u64 wu = __ballot(fabsf(v) < CONV1_MARGIN);
            if (lane == 0) {
                size_t widx = ((size_t)n * 482 + lp) * 4 + wv;
                opk64[widx] = wb;
                uflag64[widx] = wu;
            }
        }
    }
}

// Fixup: thread per packed u64 word; recompute flagged channels in f64.
__global__ void conv1_fixup_kernel(const float* __restrict__ x,
                                   const float* __restrict__ w1,
                                   const float* __restrict__ b,
                                   const float* __restrict__ sw,
                                   const float* __restrict__ sb,
                                   const u64* __restrict__ uflag64,
                                   u64* __restrict__ opk64)
{
    int idx = blockIdx.x * blockDim.x + threadIdx.x;
    if (idx >= 128 * 482 * 4) return;
    u64 f = uflag64[idx];
    if (f == 0) return;
    int og = idx & 3;
    int lp = (idx >> 2) % 482;
    int n = idx / (4 * 482);
    u64 word = opk64[idx];
    const float* xb = x + (size_t)n * 3 * 2560;
    while (f) {
        int c = __ffsll(f) - 1;
        f &= f - 1;
        int co = og * 64 + c;
        const float* wp = w1 + (size_t)co * 69;
        double best = -1e300;
        for (int t = 0; t < 5; ++t) {
            int gl = 5 * lp - 2 + t;
            if (gl < 0 || gl >= 2406) continue;
            double s = 0.0;
            #pragma unroll
            for (int ci = 0; ci < 3; ++ci) {
                const float* xp = xb + ci * 2560 + gl;
                const float* wq = wp + ci * 23;
                #pragma unroll
                for (int kk = 0; kk < 23; ++kk) {
                    double xv = (double)xp[kk * 7];
                    s += (wq[kk] >= 0.0f) ? xv : -xv;
                }
            }
            best = fmax(best, s);
        }
        double v = ((sw[co] >= 0.0f) ? 0.1 : -0.1) * (0.1 * best + (double)b[co]) + (double)sb[co];
        u64 bit = (v >= 0.0) ? 1ull : 0ull;
        word = (word & ~(1ull << c)) | (bit << c);
    }
    opk64[idx] = word;
}

// -------------------- binary conv layers 2,3 (XNOR-popcount) ---------------
// One wave = 64 output channels x LPW pooled positions at one (n,og).
template<int K, int DIL, int PK, int PP, int W, int LPW>
__global__ void bconv_bit_kernel(const u64* __restrict__ apk,  // [N][Lin][W]
                                 const u64* __restrict__ wpk,  // [K][Cout][W]
                                 const float* __restrict__ b,
                                 const float* __restrict__ sw,
                                 const float* __restrict__ sb,
                                 u64* __restrict__ opk,        // [N][Lout][Cout/64]
                                 int Cout, int Lin, int Lconv, int Lout,
                                 int NLPG, int nwaves)
{
    int wid = __builtin_amdgcn_readfirstlane(
        (int)(blockIdx.x * (blockDim.x >> 6)) + (int)(threadIdx.x >> 6));
    int lane = threadIdx.x & 63;
    if (wid >= nwaves) return;
    int WOUT = Cout >> 6;
    int og = wid % WOUT;
    int lpg = (wid / WOUT) % NLPG;
    int n  = wid / (WOUT * NLPG);
    int lp0 = lpg * LPW;
    int co = og * 64 + lane;

    const u64* ab = apk + (size_t)n * Lin * W;
    int cnt[LPW][PK];
    #pragma unroll
    for (int j = 0; j < LPW; ++j)
        #pragma unroll
        for (int t = 0; t < PK; ++t) cnt[j][t] = 0;

    #pragma unroll
    for (int k = 0; k < K; ++k) {
        u64 ww[W];
        #pragma unroll
        for (int w = 0; w < W; ++w)
            ww[w] = wpk[((size_t)k * Cout + co) * W + w];
        #pragma unroll
        for (int j = 0; j < LPW; ++j) {
            int lp = lp0 + j;
            #pragma unroll
            for (int t = 0; t < PK; ++t) {
                int l = lp * PK - PP + t;
                if (lp >= Lout || l < 0 || l >= Lconv) continue;
                const u64* ap = ab + (size_t)(l + k * DIL) * W;
                #pragma unroll
                for (int w = 0; w < W; ++w)
                    cnt[j][t] += __popcll(ap[w] ^ ww[w]);
            }
        }
    }
    const int CINK = W * 64 * K;
    #pragma unroll
    for (int j = 0; j < LPW; ++j) {
        int lp = lp0 + j;
        int best = -2147483647;
        #pragma unroll
        for (int t = 0; t < PK; ++t) {
            int l = lp * PK - PP + t;
            if (l < 0 || l >= Lconv) continue;
            int ksum = CINK - 2 * cnt[j][t];
            best = (ksum > best) ? ksum : best;
        }
        bool bit = false;
        if (lp < Lout) {
            double conv = 0.1 * (double)best + (double)b[co];
            double v = ((sw[co] >= 0.0f) ? 0.1 : -0.1) * conv + (double)sb[co];
            bit = (v >= 0.0);
        }
        u64 word = __ballot(bit);
        if (lp < Lout && lane == 0)
            opk[((size_t)n * Lout + lp) * WOUT + og] = word;
    }
}

// -------------------- fused tail: layers 4,5,6 + fc1 + fc2 -----------------
// One block (256 threads) per sample n; intermediates live in LDS.
__global__ __launch_bounds__(256) void tail_kernel(
    const u64* __restrict__ a3,      // [128][46][4]
    const u64* __restrict__ wpk4,    // [5][256][4]
    const u64* __restrict__ wpk5,    // [5][256][4]
    const u64* __restrict__ wpk6,    // [3][8][4]
    const float* __restrict__ b4, const float* __restrict__ sw4, const float* __restrict__ sb4,
    const float* __restrict__ b5, const float* __restrict__ sw5, const float* __restrict__ sb5,
    const float* __restrict__ b6, const float* __restrict__ sw6, const float* __restrict__ sb6,
    const u32* __restrict__ fw1pk,   // [512]
    const float* __restrict__ fsw1, const float* __restrict__ fsb1,
    const u64* __restrict__ fpk2,    // [1000][8]
    const float* __restrict__ fsw2, const float* __restrict__ fsb2,
    float* __restrict__ out)         // [128][1000]
{
    __shared__ u64 sA[46 * 4];   // layer-4 input
    __shared__ u64 sB[42 * 4];   // layer-4 output
    __shared__ u64 sC[13 * 4];   // layer-5 output
    __shared__ u32 sA6;          // layer-6 output, 32 bits (bit = co*4+lp)
    __shared__ u64 sH[8];        // fc1 output, 512 bits
    int n = blockIdx.x, tid = threadIdx.x, lane = tid & 63, wv = tid >> 6;

    for (int i = tid; i < 46 * 4; i += 256) sA[i] = a3[(size_t)n * 46 * 4 + i];
    __syncthreads();

    // ---- layer 4: K=5, dil=1, no pool, Lconv=Lout=42, thread = channel ----
    {
        u64 ww[5][4];
        #pragma unroll
        for (int k = 0; k < 5; ++k)
            #pragma unroll
            for (int w = 0; w < 4; ++w)
                ww[k][w] = wpk4[((size_t)k * 256 + tid) * 4 + w];
        double bc = b4[tid];
        double swc = (sw4[tid] >= 0.0f) ? 0.1 : -0.1;
        double sbc = sb4[tid];
        for (int lp = 0; lp < 42; ++lp) {
            int cnt = 0;
            #pragma unroll
            for (int k = 0; k < 5; ++k)
                #pragma unroll
                for (int w = 0; w < 4; ++w)
                    cnt += __popcll(sA[(lp + k) * 4 + w] ^ ww[k][w]);
            int ksum = 256 * 5 - 2 * cnt;
            double v = swc * (0.1 * ksum + bc) + sbc;
            u64 word = __ballot(v >= 0.0);
            if (lane == 0) sB[lp * 4 + wv] = word;
        }
    }
    __syncthreads();

    // ---- layer 5: K=5, pool(3,1), Lconv=38, Lout=13, thread = channel ----
    {
        u64 ww[5][4];
        #pragma unroll
        for (int k = 0; k < 5; ++k)
            #pragma unroll
            for (int w = 0; w < 4; ++w)
                ww[k][w] = wpk5[((size_t)k * 256 + tid) * 4 + w];
        double bc = b5[tid];
        double swc = (sw5[tid] >= 0.0f) ? 0.1 : -0.1;
        double sbc = sb5[tid];
        for (int lp = 0; lp < 13; ++lp) {
            int best = -2147483647;
            #pragma unroll
            for (int t = 0; t < 3; ++t) {
                int l = 3 * lp - 1 + t;
                if (l < 0 || l >= 38) continue;
                int cnt = 0;
                #pragma unroll
                for (int k = 0; k < 5; ++k)
                    #pragma unroll
                    for (int w = 0; w < 4; ++w)
                        cnt += __popcll(sB[(l + k) * 4 + w] ^ ww[k][w]);
                int ksum = 256 * 5 - 2 * cnt;
                best = (ksum > best) ? ksum : best;
            }
            double v = swc * (0.1 * best + bc) + sbc;
            u64 word = __ballot(v >= 0.0);
            if (lane == 0) sC[lp * 4 + wv] = word;
        }
    }
    __syncthreads();

    // ---- layer 6: Cout=8, K=3, pool(3,1), Lconv=11, Lout=4 ----
    if (tid < 32) {
        int co = tid >> 2, lp = tid & 3;
        int best = -2147483647;
        for (int t = 0; t < 3; ++t) {
            int l = 3 * lp - 1 + t;
            if (l < 0 || l >= 11) continue;
            int cnt = 0;
            #pragma unroll
            for (int k = 0; k < 3; ++k)
                #pragma unroll
                for (int w = 0; w < 4; ++w)
                    cnt += __popcll(sC[(l + k) * 4 + w] ^ wpk6[((size_t)k * 8 + co) * 4 + w]);
            int ksum = 256 * 3 - 2 * cnt;
            best = (ksum > best) ? ksum : best;
        }
        double v = ((sw6[co] >= 0.0f) ? 0.1 : -0.1) * (0.1 * best + (double)b6[co]) + (double)sb6[co];
        u64 word = __ballot(v >= 0.0);   // bit index = tid = co*4+lp (reshape order)
        if (tid == 0) sA6 = (u32)word;
    }
    __syncthreads();

    // ---- fc1: 512 outputs, 32-bit xnor-popcount ----
    {
        u32 a6w = sA6;
        #pragma unroll
        for (int p = 0; p < 2; ++p) {
            int o = tid + p * 256;
            int k = 32 - 2 * __popc(a6w ^ fw1pk[o]);
            double v = ((fsw1[o] >= 0.0f) ? 0.1 : -0.1) * (0.1 * (double)k) + (double)fsb1[o];
            u64 word = __ballot(v >= 0.0);
            if (lane == 0) sH[p * 4 + wv] = word;
        }
    }
    __syncthreads();

    // ---- fc2: 1000 outputs, 512-bit xnor-popcount, f32 store ----
    {
        u64 h[8];
        #pragma unroll
        for (int w = 0; w < 8; ++w) h[w] = sH[w];
        #pragma unroll
        for (int p = 0; p < 4; ++p) {
            int o = tid + p * 256;
            if (o < 1000) {
                int cnt = 0;
                #pragma unroll
                for (int w = 0; w < 8; ++w)
                    cnt += __popcll(h[w] ^ fpk2[(size_t)o * 8 + w]);
                int k = 512 - 2 * cnt;
                double v = ((fsw2[o] >= 0.0f) ? 0.1 : -0.1) * (0.1 * (double)k) + (double)fsb2[o];
                out[(size_t)n * 1000 + o] = (float)v;
            }
        }
    }
}

extern "C" void kernel_launch(void* const* d_in, const int* in_sizes, int n_in,
                              void* d_out, int out_size, void* d_ws, size_t ws_size,
                              hipStream_t stream) {
    const float* x = (const float*)d_in[0];
    const float *w[6], *b[6], *sw[6], *sb[6];
    for (int i = 0; i < 6; ++i) {
        w[i]  = (const float*)d_in[1 + 4 * i];
        b[i]  = (const float*)d_in[2 + 4 * i];
        sw[i] = (const float*)d_in[3 + 4 * i];
        sb[i] = (const float*)d_in[4 + 4 * i];
    }
    const float* fw1  = (const float*)d_in[25];
    const float* fsw1 = (const float*)d_in[26];
    const float* fsb1 = (const float*)d_in[27];
    const float* fw2  = (const float*)d_in[28];
    const float* fsw2 = (const float*)d_in[29];
    const float* fsb2 = (const float*)d_in[30];
    float* out = (float*)d_out;
    (void)in_sizes; (void)n_in; (void)out_size; (void)ws_size;

    char* wsbase = (char*)d_ws;
    size_t off = 0;
    auto alloc = [&](size_t bytes) -> char* {
        char* p = wsbase + off;
        off = (off + bytes + 255) & ~(size_t)255;
        return p;
    };
    u64* wpk2 = (u64*)alloc((size_t)13 * 256 * 4 * 8);
    u64* wpk3 = (u64*)alloc((size_t)7 * 256 * 4 * 8);
    u64* wpk4 = (u64*)alloc((size_t)5 * 256 * 4 * 8);
    u64* wpk5 = (u64*)alloc((size_t)5 * 256 * 4 * 8);
    u64* wpk6 = (u64*)alloc((size_t)3 * 8 * 4 * 8);
    u64* fpk2 = (u64*)alloc((size_t)1000 * 8 * 8);
    u32* fw1pk = (u32*)alloc((size_t)512 * 4);
    float* sgnf = (float*)alloc((size_t)69 * 256 * 4);
    float* wsx  = (float*)alloc(((size_t)128 * 3 * 2560 + 32) * 4);
    u64* uflag64 = (u64*)alloc((size_t)128 * 482 * 4 * 8);
    u64* a1   = (u64*)alloc((size_t)128 * 482 * 4 * 8);
    u64* a2   = (u64*)alloc((size_t)128 * 149 * 4 * 8);
    u64* a3   = (u64*)alloc((size_t)128 * 46 * 4 * 8);

    const int BLK = 256;
    auto blocksForWaves = [](int nwaves) { return dim3((unsigned)((nwaves * 64 + 255) / 256)); };
    auto blocksForThreads = [](int n) { return dim3((unsigned)((n + 255) / 256)); };

    // merged weight packing (fc2 job expressed as K=1)
    {
        PackJobs P;
        int base = 0;
        auto setJob = [&](int i, const float* src, u64* dst, int Cout, int CIN, int K) {
            P.j[i] = {src, dst, Cout, CIN, K, base};
            base += K * Cout * (CIN >> 6);
        };
        setJob(0, w[1], wpk2, 256, 256, 13);
        setJob(1, w[2], wpk3, 256, 256, 7);
        setJob(2, w[3], wpk4, 256, 256, 5);
        setJob(3, w[4], wpk5, 256, 256, 5);
        setJob(4, w[5], wpk6, 8, 256, 3);
        setJob(5, fw2, fpk2, 1000, 512, 1);
        P.totalWaves = base;
        pack_all_kernel<<<blocksForWaves(base), BLK, 0, stream>>>(P);
    }
    packfc1_kernel<<<dim3(2), BLK, 0, stream>>>(fw1, fw1pk);
    pack_sgn1_kernel<<<blocksForThreads(256 * 69), BLK, 0, stream>>>(w[0], sgnf);
    padx_kernel<<<blocksForThreads(128 * 3 * 2560), BLK, 0, stream>>>(x, wsx);

    // layer 1: per-lane-weight f32 pass (x via SGPR) + f64 fixup of near-zero
    conv1_pass1_kernel<<<dim3(128, 31), BLK, 0, stream>>>(
        wsx, sgnf, b[0], sw[0], sb[0], a1, uflag64);
    conv1_fixup_kernel<<<blocksForThreads(128 * 482 * 4), BLK, 0, stream>>>(
        x, w[0], b[0], sw[0], sb[0], uflag64, a1);

    // layer 2: K=13 dil=3 pool(3,1): Lin=482 Lconv=446 Lout=149
    {
        const int NLPG = (149 + 3) / 4;
        int nw = 128 * NLPG * 4;
        bconv_bit_kernel<13, 3, 3, 1, 4, 4><<<blocksForWaves(nw), BLK, 0, stream>>>(
            a1, wpk2, b[1], sw[1], sb[1], a2, 256, 482, 446, 149, NLPG, nw);
    }
    // layer 3: K=7 dil=2 pool(3,1): Lin=149 Lconv=137 Lout=46
    {
        const int NLPG = (46 + 3) / 4;
        int nw = 128 * NLPG * 4;
        bconv_bit_kernel<7, 2, 3, 1, 4, 4><<<blocksForWaves(nw), BLK, 0, stream>>>(
            a2, wpk3, b[2], sw[2], sb[2], a3, 256, 149, 137, 46, NLPG, nw);
    }
    // fused tail: layers 4,5,6 + fc1 + fc2
    tail_kernel<<<dim3(128), BLK, 0, stream>>>(
        a3, wpk4, wpk5, wpk6,
        b[3], sw[3], sb[3], b[4], sw[4], sb[4], b[5], sw[5], sb[5],
        fw1pk, fsw1, fsb1, fpk2, fsw2, fsb2, out);
}

// Round 10
// 424.898 us; speedup vs baseline: 1.9547x; 1.9547x over previous
//
#include <hip/hip_runtime.h>
#include <cstdint>
#include <cstddef>

typedef unsigned long long u64;
typedef uint32_t u32;
typedef uint16_t u16;
typedef uint8_t u8;

// ---------------------------------------------------------------------------
// Binary AlexNet-1D. bq(w)=0.1*sign(w), bact(x)=sign(x). All binary layers are
// exact integer XNOR-popcount + f64 affine epilogue. Activations bitpacked as
// [N][L][C/64] u64. Conv sum = CIN*K - 2*popc(a^w); maxpool (stride==kernel,
// scale 0.1>0) commutes with the affine map, so pool the integer sums.
// Layer 1 (real f32 input): register-tiled f32 FMA pass. Thread owns 16 ch x
// 5 conv positions (= one pool window; acc[16][5] in VGPRs). waves_per_eu(1,2)
// raises the VGPR budget to ~256 so the accumulator tile is arch-VGPR-resident
// (no AGPR round-trips, the 2-ops/acc overhead seen in rounds 4/7/8).
// Weights +-1.0f in LDS (uniform-address float4 broadcast), x in LDS tile.
// Near-zero outputs (|v| < margin) recomputed in f64 by a fixup kernel ->
// sign decisions stay f64-exact.
// Layers 4..6 + fc1 + fc2 fused into one block-per-sample kernel (LDS).
// ---------------------------------------------------------------------------

#define CONV1_MARGIN 1e-4f

// -------------------- merged weight packing --------------------
// packs w[Cout][CIN][K] float -> wpk[K][Cout][CIN/64]; fc layers use K=1.
struct PackJob { const float* src; u64* dst; int Cout, CIN, K, waveBase; };
struct PackJobs { PackJob j[6]; int totalWaves; };

__global__ void pack_all_kernel(PackJobs P)
{
    int gtid = blockIdx.x * blockDim.x + threadIdx.x;
    int wid = gtid >> 6, lane = gtid & 63;
    if (wid >= P.totalWaves) return;
    int jj = 0;
    #pragma unroll
    for (int i = 1; i < 6; ++i) if (wid >= P.j[i].waveBase) jj = i;
    PackJob job = P.j[jj];
    int lw = wid - job.waveBase;
    int W = job.CIN >> 6;
    int wg = lw % W;
    int co = (lw / W) % job.Cout;
    int k  = lw / (W * job.Cout);
    int ci = wg * 64 + lane;
    bool sg = job.src[((size_t)co * job.CIN + ci) * job.K + k] >= 0.0f;
    u64 word = __ballot(sg);
    if (lane == 0) job.dst[lw] = word;
}

// misc packing: fc1 sign masks (u32[512]) + layer-1 sign floats [16][69][16]
__global__ void pack_misc_kernel(const float* __restrict__ fw1, u32* __restrict__ fw1pk,
                                 const float* __restrict__ w1, float* __restrict__ sgnf)
{
    int idx = blockIdx.x * blockDim.x + threadIdx.x;
    if (idx < 512) {
        u32 wd = 0;
        #pragma unroll
        for (int i = 0; i < 32; ++i) wd |= (u32)(fw1[idx * 32 + i] >= 0.0f) << i;
        fw1pk[idx] = wd;
    }
    int j = idx - 512;
    if (j >= 0 && j < 256 * 69) {
        int i = j % 69, co = j / 69;
        sgnf[(size_t)(co >> 4) * 69 * 16 + i * 16 + (co & 15)] =
            (w1[(size_t)co * 69 + i] >= 0.0f) ? 1.0f : -1.0f;
    }
}

// -------------------- layer 1 --------------------
// grid (n=128, bl=2, chunk=16), block 256. Thread tid -> pooled output
// lp = 256*bl + tid for 16 channels [16*chunk, 16*chunk+16).
// conv positions l = 5*lp-2+j, j=0..4 (one pool window, thread-local max).
// x tile + 16-channel weight tile in LDS; acc[16][5] in VGPRs.
__global__ __launch_bounds__(256)
__attribute__((amdgpu_waves_per_eu(1, 2)))
void conv1_pass1_kernel(
    const float* __restrict__ x, const float* __restrict__ sgnf,
    const float* __restrict__ b, const float* __restrict__ sw,
    const float* __restrict__ sb,
    u16* __restrict__ opk16, u16* __restrict__ uflag16)
{
    __shared__ float xt[3 * 1440];
    __shared__ float wt[69 * 16];
    const int Lin = 2560, Lconv = 2406;
    int n = blockIdx.x, bl = blockIdx.y, chunk = blockIdx.z;
    int tid = threadIdx.x;
    int base = 1280 * bl - 2;

    // stage x tile (source index clamped; clamped values are only ever read
    // by conv positions that the pooling max later excludes)
    const float* xb = x + (size_t)n * 3 * Lin;
    for (int idx = tid; idx < 3 * 1440; idx += 256) {
        int ci = idx / 1440, rel = idx - ci * 1440;
        int src = min(max(base + rel, 0), Lin - 1);
        xt[idx] = xb[ci * Lin + src];
    }
    // stage weight signs (+-1.0f), layout already [i][c] for this chunk
    for (int idx = tid; idx < 69 * 16; idx += 256)
        wt[idx] = sgnf[(size_t)chunk * 69 * 16 + idx];
    __syncthreads();

    float acc[16][5];
    #pragma unroll
    for (int c = 0; c < 16; ++c)
        #pragma unroll
        for (int j = 0; j < 5; ++j) acc[c][j] = 0.0f;

    const float* xrow = xt + 5 * tid;
    #pragma unroll 1
    for (int ci = 0; ci < 3; ++ci) {
        #pragma unroll
        for (int kk = 0; kk < 23; ++kk) {
            float xv[5];
            #pragma unroll
            for (int j = 0; j < 5; ++j)
                xv[j] = xrow[ci * 1440 + 7 * kk + j];
            const float4* wrow = (const float4*)(wt + (ci * 23 + kk) * 16);
            #pragma unroll
            for (int g = 0; g < 4; ++g) {
                float4 wv = wrow[g];
                #pragma unroll
                for (int j = 0; j < 5; ++j) {
                    acc[g * 4 + 0][j] = fmaf(xv[j], wv.x, acc[g * 4 + 0][j]);
                    acc[g * 4 + 1][j] = fmaf(xv[j], wv.y, acc[g * 4 + 1][j]);
                    acc[g * 4 + 2][j] = fmaf(xv[j], wv.z, acc[g * 4 + 2][j]);
                    acc[g * 4 + 3][j] = fmaf(xv[j], wv.w, acc[g * 4 + 3][j]);
                }
            }
        }
    }

    int lp = 256 * bl + tid;
    if (lp < 482) {
        u32 bits = 0, uncs = 0;
        #pragma unroll
        for (int c = 0; c < 16; ++c) {
            int co = chunk * 16 + c;
            float best = -1e30f;
            #pragma unroll
            for (int j = 0; j < 5; ++j) {
                int l = 5 * lp - 2 + j;
                if (l >= 0 && l < Lconv) best = fmaxf(best, acc[c][j]);
            }
            float v = ((sw[co] >= 0.0f) ? 0.1f : -0.1f) * (0.1f * best + b[co]) + sb[co];
            bits |= (v >= 0.0f ? 1u : 0u) << c;
            uncs |= (fabsf(v) < CONV1_MARGIN ? 1u : 0u) << c;
        }
        size_t widx = ((size_t)n * 482 + lp) * 16 + chunk;
        opk16[widx] = (u16)bits;
        uflag16[widx] = (u16)uncs;
    }
}

// Fixup: thread per packed u16 word; recompute flagged channels in f64.
__global__ void conv1_fixup_kernel(const float* __restrict__ x,
                                   const float* __restrict__ w1,
                                   const float* __restrict__ b,
                                   const float* __restrict__ sw,
                                   const float* __restrict__ sb,
                                   const u16* __restrict__ uflag16,
                                   u16* __restrict__ opk16)
{
    int idx = blockIdx.x * blockDim.x + threadIdx.x;
    if (idx >= 128 * 482 * 16) return;
    u32 f = uflag16[idx];
    if (f == 0) return;
    int chunk = idx & 15;
    int lp = (idx >> 4) % 482;
    int n = idx / (16 * 482);
    u32 word = opk16[idx];
    const float* xb = x + (size_t)n * 3 * 2560;
    while (f) {
        int c = __ffs(f) - 1;
        f &= f - 1;
        int co = chunk * 16 + c;
        const float* wp = w1 + (size_t)co * 69;
        double best = -1e300;
        for (int t = 0; t < 5; ++t) {
            int gl = 5 * lp - 2 + t;
            if (gl < 0 || gl >= 2406) continue;
            double s = 0.0;
            #pragma unroll
            for (int ci = 0; ci < 3; ++ci) {
                const float* xp = xb + ci * 2560 + gl;
                const float* wq = wp + ci * 23;
                #pragma unroll
                for (int kk = 0; kk < 23; ++kk) {
                    double xv = (double)xp[kk * 7];
                    s += (wq[kk] >= 0.0f) ? xv : -xv;
                }
            }
            best = fmax(best, s);
        }
        double v = ((sw[co] >= 0.0f) ? 0.1 : -0.1) * (0.1 * best + (double)b[co]) + (double)sb[co];
        u32 bit = (v >= 0.0) ? 1u : 0u;
        word = (word & ~(1u << c)) | (bit << c);
    }
    opk16[idx] = word;
}

// -------------------- binary conv layers 2,3 (XNOR-popcount) ---------------
// One wave = 64 output channels x LPW pooled positions at one (n,og).
template<int K, int DIL, int PK, int PP, int W, int LPW>
__global__ void bconv_bit_kernel(const u64* __restrict__ apk,  // [N][Lin][W]
                                 const u64* __restrict__ wpk,  // [K][Cout][W]
                                 const float* __restrict__ b,
                                 const float* __restrict__ sw,
                                 const float* __restrict__ sb,
                                 u64* __restrict__ opk,        // [N][Lout][Cout/64]
                                 int Cout, int Lin, int Lconv, int Lout,
                                 int NLPG, int nwaves)
{
    int wid = __builtin_amdgcn_readfirstlane(
        (int)(blockIdx.x * (blockDim.x >> 6)) + (int)(threadIdx.x >> 6));
    int lane = threadIdx.x & 63;
    if (wid >= nwaves) return;
    int WOUT = Cout >> 6;
    int og = wid % WOUT;
    int lpg = (wid / WOUT) % NLPG;
    int n  = wid / (WOUT * NLPG);
    int lp0 = lpg * LPW;
    int co = og * 64 + lane;

    const u64* ab = apk + (size_t)n * Lin * W;
    int cnt[LPW][PK];
    #pragma unroll
    for (int j = 0; j < LPW; ++j)
        #pragma unroll
        for (int t = 0; t < PK; ++t) cnt[j][t] = 0;

    #pragma unroll
    for (int k = 0; k < K; ++k) {
        u64 ww[W];
        #pragma unroll
        for (int w = 0; w < W; ++w)
            ww[w] = wpk[((size_t)k * Cout + co) * W + w];
        #pragma unroll
        for (int j = 0; j < LPW; ++j) {
            int lp = lp0 + j;
            #pragma unroll
            for (int t = 0; t < PK; ++t) {
                int l = lp * PK - PP + t;
                if (lp >= Lout || l < 0 || l >= Lconv) continue;
                const u64* ap = ab + (size_t)(l + k * DIL) * W;
                #pragma unroll
                for (int w = 0; w < W; ++w)
                    cnt[j][t] += __popcll(ap[w] ^ ww[w]);
            }
        }
    }
    const int CINK = W * 64 * K;
    #pragma unroll
    for (int j = 0; j < LPW; ++j) {
        int lp = lp0 + j;
        int best = -2147483647;
        #pragma unroll
        for (int t = 0; t < PK; ++t) {
            int l = lp * PK - PP + t;
            if (l < 0 || l >= Lconv) continue;
            int ksum = CINK - 2 * cnt[j][t];
            best = (ksum > best) ? ksum : best;
        }
        bool bit = false;
        if (lp < Lout) {
            double conv = 0.1 * (double)best + (double)b[co];
            double v = ((sw[co] >= 0.0f) ? 0.1 : -0.1) * conv + (double)sb[co];
            bit = (v >= 0.0);
        }
        u64 word = __ballot(bit);
        if (lp < Lout && lane == 0)
            opk[((size_t)n * Lout + lp) * WOUT + og] = word;
    }
}

// -------------------- fused tail: layers 4,5,6 + fc1 + fc2 -----------------
// One block (256 threads) per sample n; intermediates live in LDS.
__global__ __launch_bounds__(256) void tail_kernel(
    const u64* __restrict__ a3,      // [128][46][4]
    const u64* __restrict__ wpk4,    // [5][256][4]
    const u64* __restrict__ wpk5,    // [5][256][4]
    const u64* __restrict__ wpk6,    // [3][8][4]
    const float* __restrict__ b4, const float* __restrict__ sw4, const float* __restrict__ sb4,
    const float* __restrict__ b5, const float* __restrict__ sw5, const float* __restrict__ sb5,
    const float* __restrict__ b6, const float* __restrict__ sw6, const float* __restrict__ sb6,
    const u32* __restrict__ fw1pk,   // [512]
    const float* __restrict__ fsw1, const float* __restrict__ fsb1,
    const u64* __restrict__ fpk2,    // [1000][8]
    const float* __restrict__ fsw2, const float* __restrict__ fsb2,
    float* __restrict__ out)         // [128][1000]
{
    __shared__ u64 sA[46 * 4];   // layer-4 input
    __shared__ u64 sB[42 * 4];   // layer-4 output
    __shared__ u64 sC[13 * 4];   // layer-5 output
    __shared__ u32 sA6;          // layer-6 output, 32 bits (bit = co*4+lp)
    __shared__ u64 sH[8];        // fc1 output, 512 bits
    int n = blockIdx.x, tid = threadIdx.x, lane = tid & 63, wv = tid >> 6;

    for (int i = tid; i < 46 * 4; i += 256) sA[i] = a3[(size_t)n * 46 * 4 + i];
    __syncthreads();

    // ---- layer 4: K=5, dil=1, no pool, Lconv=Lout=42, thread = channel ----
    {
        u64 ww[5][4];
        #pragma unroll
        for (int k = 0; k < 5; ++k)
            #pragma unroll
            for (int w = 0; w < 4; ++w)
                ww[k][w] = wpk4[((size_t)k * 256 + tid) * 4 + w];
        double bc = b4[tid];
        double swc = (sw4[tid] >= 0.0f) ? 0.1 : -0.1;
        double sbc = sb4[tid];
        for (int lp = 0; lp < 42; ++lp) {
            int cnt = 0;
            #pragma unroll
            for (int k = 0; k < 5; ++k)
                #pragma unroll
                for (int w = 0; w < 4; ++w)
                    cnt += __popcll(sA[(lp + k) * 4 + w] ^ ww[k][w]);
            int ksum = 256 * 5 - 2 * cnt;
            double v = swc * (0.1 * ksum + bc) + sbc;
            u64 word = __ballot(v >= 0.0);
            if (lane == 0) sB[lp * 4 + wv] = word;
        }
    }
    __syncthreads();

    // ---- layer 5: K=5, pool(3,1), Lconv=38, Lout=13, thread = channel ----
    {
        u64 ww[5][4];
        #pragma unroll
        for (int k = 0; k < 5; ++k)
            #pragma unroll
            for (int w = 0; w < 4; ++w)
                ww[k][w] = wpk5[((size_t)k * 256 + tid) * 4 + w];
        double bc = b5[tid];
        double swc = (sw5[tid] >= 0.0f) ? 0.1 : -0.1;
        double sbc = sb5[tid];
        for (int lp = 0; lp < 13; ++lp) {
            int best = -2147483647;
            #pragma unroll
            for (int t = 0; t < 3; ++t) {
                int l = 3 * lp - 1 + t;
                if (l < 0 || l >= 38) continue;
                int cnt = 0;
                #pragma unroll
                for (int k = 0; k < 5; ++k)
                    #pragma unroll
                    for (int w = 0; w < 4; ++w)
                        cnt += __popcll(sB[(l + k) * 4 + w] ^ ww[k][w]);
                int ksum = 256 * 5 - 2 * cnt;
                best = (ksum > best) ? ksum : best;
            }
            double v = swc * (0.1 * best + bc) + sbc;
            u64 word = __ballot(v >= 0.0);
            if (lane == 0) sC[lp * 4 + wv] = word;
        }
    }
    __syncthreads();

    // ---- layer 6: Cout=8, K=3, pool(3,1), Lconv=11, Lout=4 ----
    if (tid < 32) {
        int co = tid >> 2, lp = tid & 3;
        int best = -2147483647;
        for (int t = 0; t < 3; ++t) {
            int l = 3 * lp - 1 + t;
            if (l < 0 || l >= 11) continue;
            int cnt = 0;
            #pragma unroll
            for (int k = 0; k < 3; ++k)
                #pragma unroll
                for (int w = 0; w < 4; ++w)
                    cnt += __popcll(sC[(l + k) * 4 + w] ^ wpk6[((size_t)k * 8 + co) * 4 + w]);
            int ksum = 256 * 3 - 2 * cnt;
            best = (ksum > best) ? ksum : best;
        }
        double v = ((sw6[co] >= 0.0f) ? 0.1 : -0.1) * (0.1 * best + (double)b6[co]) + (double)sb6[co];
        u64 word = __ballot(v >= 0.0);   // bit index = tid = co*4+lp (reshape order)
        if (tid == 0) sA6 = (u32)word;
    }
    __syncthreads();

    // ---- fc1: 512 outputs, 32-bit xnor-popcount ----
    {
        u32 a6w = sA6;
        #pragma unroll
        for (int p = 0; p < 2; ++p) {
            int o = tid + p * 256;
            int k = 32 - 2 * __popc(a6w ^ fw1pk[o]);
            double v = ((fsw1[o] >= 0.0f) ? 0.1 : -0.1) * (0.1 * (double)k) + (double)fsb1[o];
            u64 word = __ballot(v >= 0.0);
            if (lane == 0) sH[p * 4 + wv] = word;
        }
    }
    __syncthreads();

    // ---- fc2: 1000 outputs, 512-bit xnor-popcount, f32 store ----
    {
        u64 h[8];
        #pragma unroll
        for (int w = 0; w < 8; ++w) h[w] = sH[w];
        #pragma unroll
        for (int p = 0; p < 4; ++p) {
            int o = tid + p * 256;
            if (o < 1000) {
                int cnt = 0;
                #pragma unroll
                for (int w = 0; w < 8; ++w)
                    cnt += __popcll(h[w] ^ fpk2[(size_t)o * 8 + w]);
                int k = 512 - 2 * cnt;
                double v = ((fsw2[o] >= 0.0f) ? 0.1 : -0.1) * (0.1 * (double)k) + (double)fsb2[o];
                out[(size_t)n * 1000 + o] = (float)v;
            }
        }
    }
}

extern "C" void kernel_launch(void* const* d_in, const int* in_sizes, int n_in,
                              void* d_out, int out_size, void* d_ws, size_t ws_size,
                              hipStream_t stream) {
    const float* x = (const float*)d_in[0];
    const float *w[6], *b[6], *sw[6], *sb[6];
    for (int i = 0; i < 6; ++i) {
        w[i]  = (const float*)d_in[1 + 4 * i];
        b[i]  = (const float*)d_in[2 + 4 * i];
        sw[i] = (const float*)d_in[3 + 4 * i];
        sb[i] = (const float*)d_in[4 + 4 * i];
    }
    const float* fw1  = (const float*)d_in[25];
    const float* fsw1 = (const float*)d_in[26];
    const float* fsb1 = (const float*)d_in[27];
    const float* fw2  = (const float*)d_in[28];
    const float* fsw2 = (const float*)d_in[29];
    const float* fsb2 = (const float*)d_in[30];
    float* out = (float*)d_out;
    (void)in_sizes; (void)n_in; (void)out_size; (void)ws_size;

    char* wsbase = (char*)d_ws;
    size_t off = 0;
    auto alloc = [&](size_t bytes) -> char* {
        char* p = wsbase + off;
        off = (off + bytes + 255) & ~(size_t)255;
        return p;
    };
    u64* wpk2 = (u64*)alloc((size_t)13 * 256 * 4 * 8);
    u64* wpk3 = (u64*)alloc((size_t)7 * 256 * 4 * 8);
    u64* wpk4 = (u64*)alloc((size_t)5 * 256 * 4 * 8);
    u64* wpk5 = (u64*)alloc((size_t)5 * 256 * 4 * 8);
    u64* wpk6 = (u64*)alloc((size_t)3 * 8 * 4 * 8);
    u64* fpk2 = (u64*)alloc((size_t)1000 * 8 * 8);
    u32* fw1pk = (u32*)alloc((size_t)512 * 4);
    float* sgnf = (float*)alloc((size_t)16 * 69 * 16 * 4);
    u16* uflag16 = (u16*)alloc((size_t)128 * 482 * 16 * 2);
    u64* a1   = (u64*)alloc((size_t)128 * 482 * 4 * 8);
    u64* a2   = (u64*)alloc((size_t)128 * 149 * 4 * 8);
    u64* a3   = (u64*)alloc((size_t)128 * 46 * 4 * 8);
    u16* opk16 = (u16*)a1;  // u16 word (co/16) aliases u64 word (co/64) bits

    const int BLK = 256;
    auto blocksForWaves = [](int nwaves) { return dim3((unsigned)((nwaves * 64 + 255) / 256)); };
    auto blocksForThreads = [](int n) { return dim3((unsigned)((n + 255) / 256)); };

    // merged weight packing (fc2 job expressed as K=1)
    {
        PackJobs P;
        int base = 0;
        auto setJob = [&](int i, const float* src, u64* dst, int Cout, int CIN, int K) {
            P.j[i] = {src, dst, Cout, CIN, K, base};
            base += K * Cout * (CIN >> 6);
        };
        setJob(0, w[1], wpk2, 256, 256, 13);
        setJob(1, w[2], wpk3, 256, 256, 7);
        setJob(2, w[3], wpk4, 256, 256, 5);
        setJob(3, w[4], wpk5, 256, 256, 5);
        setJob(4, w[5], wpk6, 8, 256, 3);
        setJob(5, fw2, fpk2, 1000, 512, 1);
        P.totalWaves = base;
        pack_all_kernel<<<blocksForWaves(base), BLK, 0, stream>>>(P);
    }
    pack_misc_kernel<<<blocksForThreads(512 + 256 * 69), BLK, 0, stream>>>(
        fw1, fw1pk, w[0], sgnf);

    // layer 1: register-tiled f32 pass + f64 fixup of near-zero outputs
    conv1_pass1_kernel<<<dim3(128, 2, 16), BLK, 0, stream>>>(
        x, sgnf, b[0], sw[0], sb[0], opk16, uflag16);
    conv1_fixup_kernel<<<blocksForThreads(128 * 482 * 16), BLK, 0, stream>>>(
        x, w[0], b[0], sw[0], sb[0], uflag16, opk16);

    // layer 2: K=13 dil=3 pool(3,1): Lin=482 Lconv=446 Lout=149
    {
        const int NLPG = (149 + 3) / 4;
        int nw = 128 * NLPG * 4;
        bconv_bit_kernel<13, 3, 3, 1, 4, 4><<<blocksForWaves(nw), BLK, 0, stream>>>(
            a1, wpk2, b[1], sw[1], sb[1], a2, 256, 482, 446, 149, NLPG, nw);
    }
    // layer 3: K=7 dil=2 pool(3,1): Lin=149 Lconv=137 Lout=46
    {
        const int NLPG = (46 + 3) / 4;
        int nw = 128 * NLPG * 4;
        bconv_bit_kernel<7, 2, 3, 1, 4, 4><<<blocksForWaves(nw), BLK, 0, stream>>>(
            a2, wpk3, b[2], sw[2], sb[2], a3, 256, 149, 137, 46, NLPG, nw);
    }
    // fused tail: layers 4,5,6 + fc1 + fc2
    tail_kernel<<<dim3(128), BLK, 0, stream>>>(
        a3, wpk4, wpk5, wpk6,
        b[3], sw[3], sb[3], b[4], sw[4], sb[4], b[5], sw[5], sb[5],
        fw1pk, fsw1, fsb1, fpk2, fsw2, fsb2, out);
}

// Round 11
// 424.426 us; speedup vs baseline: 1.9568x; 1.0011x over previous
//
#include <hip/hip_runtime.h>
#include <cstdint>
#include <cstddef>

typedef unsigned long long u64;
typedef uint32_t u32;
typedef uint16_t u16;
typedef uint8_t u8;

// ---------------------------------------------------------------------------
// Binary AlexNet-1D. bq(w)=0.1*sign(w), bact(x)=sign(x). All binary layers are
// exact integer XNOR-popcount + f64 affine epilogue. Activations bitpacked as
// [N][L][C/64] u64. Conv sum = CIN*K - 2*popc(a^w); maxpool (stride==kernel,
// scale 0.1>0) commutes with the affine map, so pool the integer sums.
// Layer 1 (real f32 input): register-tiled f32 FMA pass. Thread owns 16 ch x
// 5 conv positions (= one pool window; acc[16][5] in VGPRs). waves_per_eu(1,2)
// raises the VGPR budget to ~256 so the accumulator tile is arch-VGPR-resident
// (no AGPR round-trips, the 2-ops/acc overhead seen in rounds 4/7/8).
// Weights +-1.0f in LDS (uniform-address float4 broadcast), x in LDS tile.
// Near-zero outputs (|v| < margin) recomputed in f64 by a fixup kernel ->
// sign decisions stay f64-exact.
// Layers 4..6 + fc1 + fc2 fused into one block-per-sample kernel (LDS).
// ---------------------------------------------------------------------------

#define CONV1_MARGIN 1e-4f

// -------------------- merged weight packing --------------------
// packs w[Cout][CIN][K] float -> wpk[K][Cout][CIN/64]; fc layers use K=1.
struct PackJob { const float* src; u64* dst; int Cout, CIN, K, waveBase; };
struct PackJobs { PackJob j[6]; int totalWaves; };

__global__ void pack_all_kernel(PackJobs P)
{
    int gtid = blockIdx.x * blockDim.x + threadIdx.x;
    int wid = gtid >> 6, lane = gtid & 63;
    if (wid >= P.totalWaves) return;
    int jj = 0;
    #pragma unroll
    for (int i = 1; i < 6; ++i) if (wid >= P.j[i].waveBase) jj = i;
    PackJob job = P.j[jj];
    int lw = wid - job.waveBase;
    int W = job.CIN >> 6;
    int wg = lw % W;
    int co = (lw / W) % job.Cout;
    int k  = lw / (W * job.Cout);
    int ci = wg * 64 + lane;
    bool sg = job.src[((size_t)co * job.CIN + ci) * job.K + k] >= 0.0f;
    u64 word = __ballot(sg);
    if (lane == 0) job.dst[lw] = word;
}

// misc packing: fc1 sign masks (u32[512]) + layer-1 sign floats [16][69][16]
__global__ void pack_misc_kernel(const float* __restrict__ fw1, u32* __restrict__ fw1pk,
                                 const float* __restrict__ w1, float* __restrict__ sgnf)
{
    int idx = blockIdx.x * blockDim.x + threadIdx.x;
    if (idx < 512) {
        u32 wd = 0;
        #pragma unroll
        for (int i = 0; i < 32; ++i) wd |= (u32)(fw1[idx * 32 + i] >= 0.0f) << i;
        fw1pk[idx] = wd;
    }
    int j = idx - 512;
    if (j >= 0 && j < 256 * 69) {
        int i = j % 69, co = j / 69;
        sgnf[(size_t)(co >> 4) * 69 * 16 + i * 16 + (co & 15)] =
            (w1[(size_t)co * 69 + i] >= 0.0f) ? 1.0f : -1.0f;
    }
}

// -------------------- layer 1 --------------------
// grid (n=128, bl=2, chunk=16), block 256. Thread tid -> pooled output
// lp = 256*bl + tid for 16 channels [16*chunk, 16*chunk+16).
// conv positions l = 5*lp-2+j, j=0..4 (one pool window, thread-local max).
// x tile + 16-channel weight tile in LDS; acc[16][5] in VGPRs.
__global__ __launch_bounds__(256)
__attribute__((amdgpu_waves_per_eu(1, 2)))
void conv1_pass1_kernel(
    const float* __restrict__ x, const float* __restrict__ sgnf,
    const float* __restrict__ b, const float* __restrict__ sw,
    const float* __restrict__ sb,
    u16* __restrict__ opk16, u16* __restrict__ uflag16)
{
    __shared__ float xt[3 * 1440];
    __shared__ float wt[69 * 16];
    const int Lin = 2560, Lconv = 2406;
    int n = blockIdx.x, bl = blockIdx.y, chunk = blockIdx.z;
    int tid = threadIdx.x;
    int base = 1280 * bl - 2;

    // stage x tile (source index clamped; clamped values are only ever read
    // by conv positions that the pooling max later excludes)
    const float* xb = x + (size_t)n * 3 * Lin;
    for (int idx = tid; idx < 3 * 1440; idx += 256) {
        int ci = idx / 1440, rel = idx - ci * 1440;
        int src = min(max(base + rel, 0), Lin - 1);
        xt[idx] = xb[ci * Lin + src];
    }
    // stage weight signs (+-1.0f), layout already [i][c] for this chunk
    for (int idx = tid; idx < 69 * 16; idx += 256)
        wt[idx] = sgnf[(size_t)chunk * 69 * 16 + idx];
    __syncthreads();

    float acc[16][5];
    #pragma unroll
    for (int c = 0; c < 16; ++c)
        #pragma unroll
        for (int j = 0; j < 5; ++j) acc[c][j] = 0.0f;

    const float* xrow = xt + 5 * tid;
    #pragma unroll 1
    for (int ci = 0; ci < 3; ++ci) {
        #pragma unroll
        for (int kk = 0; kk < 23; ++kk) {
            float xv[5];
            #pragma unroll
            for (int j = 0; j < 5; ++j)
                xv[j] = xrow[ci * 1440 + 7 * kk + j];
            const float4* wrow = (const float4*)(wt + (ci * 23 + kk) * 16);
            #pragma unroll
            for (int g = 0; g < 4; ++g) {
                float4 wv = wrow[g];
                #pragma unroll
                for (int j = 0; j < 5; ++j) {
                    acc[g * 4 + 0][j] = fmaf(xv[j], wv.x, acc[g * 4 + 0][j]);
                    acc[g * 4 + 1][j] = fmaf(xv[j], wv.y, acc[g * 4 + 1][j]);
                    acc[g * 4 + 2][j] = fmaf(xv[j], wv.z, acc[g * 4 + 2][j]);
                    acc[g * 4 + 3][j] = fmaf(xv[j], wv.w, acc[g * 4 + 3][j]);
                }
            }
        }
    }

    int lp = 256 * bl + tid;
    if (lp < 482) {
        u32 bits = 0, uncs = 0;
        #pragma unroll
        for (int c = 0; c < 16; ++c) {
            int co = chunk * 16 + c;
            float best = -1e30f;
            #pragma unroll
            for (int j = 0; j < 5; ++j) {
                int l = 5 * lp - 2 + j;
                if (l >= 0 && l < Lconv) best = fmaxf(best, acc[c][j]);
            }
            float v = ((sw[co] >= 0.0f) ? 0.1f : -0.1f) * (0.1f * best + b[co]) + sb[co];
            bits |= (v >= 0.0f ? 1u : 0u) << c;
            uncs |= (fabsf(v) < CONV1_MARGIN ? 1u : 0u) << c;
        }
        size_t widx = ((size_t)n * 482 + lp) * 16 + chunk;
        opk16[widx] = (u16)bits;
        uflag16[widx] = (u16)uncs;
    }
}

// Fixup: thread per packed u16 word; recompute flagged channels in f64.
__global__ void conv1_fixup_kernel(const float* __restrict__ x,
                                   const float* __restrict__ w1,
                                   const float* __restrict__ b,
                                   const float* __restrict__ sw,
                                   const float* __restrict__ sb,
                                   const u16* __restrict__ uflag16,
                                   u16* __restrict__ opk16)
{
    int idx = blockIdx.x * blockDim.x + threadIdx.x;
    if (idx >= 128 * 482 * 16) return;
    u32 f = uflag16[idx];
    if (f == 0) return;
    int chunk = idx & 15;
    int lp = (idx >> 4) % 482;
    int n = idx / (16 * 482);
    u32 word = opk16[idx];
    const float* xb = x + (size_t)n * 3 * 2560;
    while (f) {
        int c = __ffs(f) - 1;
        f &= f - 1;
        int co = chunk * 16 + c;
        const float* wp = w1 + (size_t)co * 69;
        double best = -1e300;
        for (int t = 0; t < 5; ++t) {
            int gl = 5 * lp - 2 + t;
            if (gl < 0 || gl >= 2406) continue;
            double s = 0.0;
            #pragma unroll
            for (int ci = 0; ci < 3; ++ci) {
                const float* xp = xb + ci * 2560 + gl;
                const float* wq = wp + ci * 23;
                #pragma unroll
                for (int kk = 0; kk < 23; ++kk) {
                    double xv = (double)xp[kk * 7];
                    s += (wq[kk] >= 0.0f) ? xv : -xv;
                }
            }
            best = fmax(best, s);
        }
        double v = ((sw[co] >= 0.0f) ? 0.1 : -0.1) * (0.1 * best + (double)b[co]) + (double)sb[co];
        u32 bit = (v >= 0.0) ? 1u : 0u;
        word = (word & ~(1u << c)) | (bit << c);
    }
    opk16[idx] = word;
}

// -------------------- binary conv layers 2,3 (XNOR-popcount) ---------------
// One wave = 64 output channels x LPW pooled positions at one (n,og).
template<int K, int DIL, int PK, int PP, int W, int LPW>
__global__ void bconv_bit_kernel(const u64* __restrict__ apk,  // [N][Lin][W]
                                 const u64* __restrict__ wpk,  // [K][Cout][W]
                                 const float* __restrict__ b,
                                 const float* __restrict__ sw,
                                 const float* __restrict__ sb,
                                 u64* __restrict__ opk,        // [N][Lout][Cout/64]
                                 int Cout, int Lin, int Lconv, int Lout,
                                 int NLPG, int nwaves)
{
    int wid = __builtin_amdgcn_readfirstlane(
        (int)(blockIdx.x * (blockDim.x >> 6)) + (int)(threadIdx.x >> 6));
    int lane = threadIdx.x & 63;
    if (wid >= nwaves) return;
    int WOUT = Cout >> 6;
    int og = wid % WOUT;
    int lpg = (wid / WOUT) % NLPG;
    int n  = wid / (WOUT * NLPG);
    int lp0 = lpg * LPW;
    int co = og * 64 + lane;

    const u64* ab = apk + (size_t)n * Lin * W;
    int cnt[LPW][PK];
    #pragma unroll
    for (int j = 0; j < LPW; ++j)
        #pragma unroll
        for (int t = 0; t < PK; ++t) cnt[j][t] = 0;

    #pragma unroll
    for (int k = 0; k < K; ++k) {
        u64 ww[W];
        #pragma unroll
        for (int w = 0; w < W; ++w)
            ww[w] = wpk[((size_t)k * Cout + co) * W + w];
        #pragma unroll
        for (int j = 0; j < LPW; ++j) {
            int lp = lp0 + j;
            #pragma unroll
            for (int t = 0; t < PK; ++t) {
                int l = lp * PK - PP + t;
                if (lp >= Lout || l < 0 || l >= Lconv) continue;
                const u64* ap = ab + (size_t)(l + k * DIL) * W;
                #pragma unroll
                for (int w = 0; w < W; ++w)
                    cnt[j][t] += __popcll(ap[w] ^ ww[w]);
            }
        }
    }
    const int CINK = W * 64 * K;
    #pragma unroll
    for (int j = 0; j < LPW; ++j) {
        int lp = lp0 + j;
        int best = -2147483647;
        #pragma unroll
        for (int t = 0; t < PK; ++t) {
            int l = lp * PK - PP + t;
            if (l < 0 || l >= Lconv) continue;
            int ksum = CINK - 2 * cnt[j][t];
            best = (ksum > best) ? ksum : best;
        }
        bool bit = false;
        if (lp < Lout) {
            double conv = 0.1 * (double)best + (double)b[co];
            double v = ((sw[co] >= 0.0f) ? 0.1 : -0.1) * conv + (double)sb[co];
            bit = (v >= 0.0);
        }
        u64 word = __ballot(bit);
        if (lp < Lout && lane == 0)
            opk[((size_t)n * Lout + lp) * WOUT + og] = word;
    }
}

// -------------------- fused tail: layers 4,5,6 + fc1 + fc2 -----------------
// One block (256 threads) per sample n; intermediates live in LDS.
__global__ __launch_bounds__(256) void tail_kernel(
    const u64* __restrict__ a3,      // [128][46][4]
    const u64* __restrict__ wpk4,    // [5][256][4]
    const u64* __restrict__ wpk5,    // [5][256][4]
    const u64* __restrict__ wpk6,    // [3][8][4]
    const float* __restrict__ b4, const float* __restrict__ sw4, const float* __restrict__ sb4,
    const float* __restrict__ b5, const float* __restrict__ sw5, const float* __restrict__ sb5,
    const float* __restrict__ b6, const float* __restrict__ sw6, const float* __restrict__ sb6,
    const u32* __restrict__ fw1pk,   // [512]
    const float* __restrict__ fsw1, const float* __restrict__ fsb1,
    const u64* __restrict__ fpk2,    // [1000][8]
    const float* __restrict__ fsw2, const float* __restrict__ fsb2,
    float* __restrict__ out)         // [128][1000]
{
    __shared__ u64 sA[46 * 4];   // layer-4 input
    __shared__ u64 sB[42 * 4];   // layer-4 output
    __shared__ u64 sC[13 * 4];   // layer-5 output
    __shared__ u32 sA6;          // layer-6 output, 32 bits (bit = co*4+lp)
    __shared__ u64 sH[8];        // fc1 output, 512 bits
    int n = blockIdx.x, tid = threadIdx.x, lane = tid & 63, wv = tid >> 6;

    for (int i = tid; i < 46 * 4; i += 256) sA[i] = a3[(size_t)n * 46 * 4 + i];
    __syncthreads();

    // ---- layer 4: K=5, dil=1, no pool, Lconv=Lout=42, thread = channel ----
    {
        u64 ww[5][4];
        #pragma unroll
        for (int k = 0; k < 5; ++k)
            #pragma unroll
            for (int w = 0; w < 4; ++w)
                ww[k][w] = wpk4[((size_t)k * 256 + tid) * 4 + w];
        double bc = b4[tid];
        double swc = (sw4[tid] >= 0.0f) ? 0.1 : -0.1;
        double sbc = sb4[tid];
        for (int lp = 0; lp < 42; ++lp) {
            int cnt = 0;
            #pragma unroll
            for (int k = 0; k < 5; ++k)
                #pragma unroll
                for (int w = 0; w < 4; ++w)
                    cnt += __popcll(sA[(lp + k) * 4 + w] ^ ww[k][w]);
            int ksum = 256 * 5 - 2 * cnt;
            double v = swc * (0.1 * ksum + bc) + sbc;
            u64 word = __ballot(v >= 0.0);
            if (lane == 0) sB[lp * 4 + wv] = word;
        }
    }
    __syncthreads();

    // ---- layer 5: K=5, pool(3,1), Lconv=38, Lout=13, thread = channel ----
    {
        u64 ww[5][4];
        #pragma unroll
        for (int k = 0; k < 5; ++k)
            #pragma unroll
            for (int w = 0; w < 4; ++w)
                ww[k][w] = wpk5[((size_t)k * 256 + tid) * 4 + w];
        double bc = b5[tid];
        double swc = (sw5[tid] >= 0.0f) ? 0.1 : -0.1;
        double sbc = sb5[tid];
        for (int lp = 0; lp < 13; ++lp) {
            int best = -2147483647;
            #pragma unroll
            for (int t = 0; t < 3; ++t) {
                int l = 3 * lp - 1 + t;
                if (l < 0 || l >= 38) continue;
                int cnt = 0;
                #pragma unroll
                for (int k = 0; k < 5; ++k)
                    #pragma unroll
                    for (int w = 0; w < 4; ++w)
                        cnt += __popcll(sB[(l + k) * 4 + w] ^ ww[k][w]);
                int ksum = 256 * 5 - 2 * cnt;
                best = (ksum > best) ? ksum : best;
            }
            double v = swc * (0.1 * best + bc) + sbc;
            u64 word = __ballot(v >= 0.0);
            if (lane == 0) sC[lp * 4 + wv] = word;
        }
    }
    __syncthreads();

    // ---- layer 6: Cout=8, K=3, pool(3,1), Lconv=11, Lout=4 ----
    if (tid < 32) {
        int co = tid >> 2, lp = tid & 3;
        int best = -2147483647;
        for (int t = 0; t < 3; ++t) {
            int l = 3 * lp - 1 + t;
            if (l < 0 || l >= 11) continue;
            int cnt = 0;
            #pragma unroll
            for (int k = 0; k < 3; ++k)
                #pragma unroll
                for (int w = 0; w < 4; ++w)
                    cnt += __popcll(sC[(l + k) * 4 + w] ^ wpk6[((size_t)k * 8 + co) * 4 + w]);
            int ksum = 256 * 3 - 2 * cnt;
            best = (ksum > best) ? ksum : best;
        }
        double v = ((sw6[co] >= 0.0f) ? 0.1 : -0.1) * (0.1 * best + (double)b6[co]) + (double)sb6[co];
        u64 word = __ballot(v >= 0.0);   // bit index = tid = co*4+lp (reshape order)
        if (tid == 0) sA6 = (u32)word;
    }
    __syncthreads();

    // ---- fc1: 512 outputs, 32-bit xnor-popcount ----
    {
        u32 a6w = sA6;
        #pragma unroll
        for (int p = 0; p < 2; ++p) {
            int o = tid + p * 256;
            int k = 32 - 2 * __popc(a6w ^ fw1pk[o]);
            double v = ((fsw1[o] >= 0.0f) ? 0.1 : -0.1) * (0.1 * (double)k) + (double)fsb1[o];
            u64 word = __ballot(v >= 0.0);
            if (lane == 0) sH[p * 4 + wv] = word;
        }
    }
    __syncthreads();

    // ---- fc2: 1000 outputs, 512-bit xnor-popcount, f32 store ----
    {
        u64 h[8];
        #pragma unroll
        for (int w = 0; w < 8; ++w) h[w] = sH[w];
        #pragma unroll
        for (int p = 0; p < 4; ++p) {
            int o = tid + p * 256;
            if (o < 1000) {
                int cnt = 0;
                #pragma unroll
                for (int w = 0; w < 8; ++w)
                    cnt += __popcll(h[w] ^ fpk2[(size_t)o * 8 + w]);
                int k = 512 - 2 * cnt;
                double v = ((fsw2[o] >= 0.0f) ? 0.1 : -0.1) * (0.1 * (double)k) + (double)fsb2[o];
                out[(size_t)n * 1000 + o] = (float)v;
            }
        }
    }
}

extern "C" void kernel_launch(void* const* d_in, const int* in_sizes, int n_in,
                              void* d_out, int out_size, void* d_ws, size_t ws_size,
                              hipStream_t stream) {
    const float* x = (const float*)d_in[0];
    const float *w[6], *b[6], *sw[6], *sb[6];
    for (int i = 0; i < 6; ++i) {
        w[i]  = (const float*)d_in[1 + 4 * i];
        b[i]  = (const float*)d_in[2 + 4 * i];
        sw[i] = (const float*)d_in[3 + 4 * i];
        sb[i] = (const float*)d_in[4 + 4 * i];
    }
    const float* fw1  = (const float*)d_in[25];
    const float* fsw1 = (const float*)d_in[26];
    const float* fsb1 = (const float*)d_in[27];
    const float* fw2  = (const float*)d_in[28];
    const float* fsw2 = (const float*)d_in[29];
    const float* fsb2 = (const float*)d_in[30];
    float* out = (float*)d_out;
    (void)in_sizes; (void)n_in; (void)out_size; (void)ws_size;

    char* wsbase = (char*)d_ws;
    size_t off = 0;
    auto alloc = [&](size_t bytes) -> char* {
        char* p = wsbase + off;
        off = (off + bytes + 255) & ~(size_t)255;
        return p;
    };
    u64* wpk2 = (u64*)alloc((size_t)13 * 256 * 4 * 8);
    u64* wpk3 = (u64*)alloc((size_t)7 * 256 * 4 * 8);
    u64* wpk4 = (u64*)alloc((size_t)5 * 256 * 4 * 8);
    u64* wpk5 = (u64*)alloc((size_t)5 * 256 * 4 * 8);
    u64* wpk6 = (u64*)alloc((size_t)3 * 8 * 4 * 8);
    u64* fpk2 = (u64*)alloc((size_t)1000 * 8 * 8);
    u32* fw1pk = (u32*)alloc((size_t)512 * 4);
    float* sgnf = (float*)alloc((size_t)16 * 69 * 16 * 4);
    u16* uflag16 = (u16*)alloc((size_t)128 * 482 * 16 * 2);
    u64* a1   = (u64*)alloc((size_t)128 * 482 * 4 * 8);
    u64* a2   = (u64*)alloc((size_t)128 * 149 * 4 * 8);
    u64* a3   = (u64*)alloc((size_t)128 * 46 * 4 * 8);
    u16* opk16 = (u16*)a1;  // u16 word (co/16) aliases u64 word (co/64) bits

    const int BLK = 256;
    auto blocksForWaves = [](int nwaves) { return dim3((unsigned)((nwaves * 64 + 255) / 256)); };
    auto blocksForThreads = [](int n) { return dim3((unsigned)((n + 255) / 256)); };

    // merged weight packing (fc2 job expressed as K=1)
    {
        PackJobs P;
        int base = 0;
        auto setJob = [&](int i, const float* src, u64* dst, int Cout, int CIN, int K) {
            P.j[i] = {src, dst, Cout, CIN, K, base};
            base += K * Cout * (CIN >> 6);
        };
        setJob(0, w[1], wpk2, 256, 256, 13);
        setJob(1, w[2], wpk3, 256, 256, 7);
        setJob(2, w[3], wpk4, 256, 256, 5);
        setJob(3, w[4], wpk5, 256, 256, 5);
        setJob(4, w[5], wpk6, 8, 256, 3);
        setJob(5, fw2, fpk2, 1000, 512, 1);
        P.totalWaves = base;
        pack_all_kernel<<<blocksForWaves(base), BLK, 0, stream>>>(P);
    }
    pack_misc_kernel<<<blocksForThreads(512 + 256 * 69), BLK, 0, stream>>>(
        fw1, fw1pk, w[0], sgnf);

    // layer 1: register-tiled f32 pass + f64 fixup of near-zero outputs
    conv1_pass1_kernel<<<dim3(128, 2, 16), BLK, 0, stream>>>(
        x, sgnf, b[0], sw[0], sb[0], opk16, uflag16);
    conv1_fixup_kernel<<<blocksForThreads(128 * 482 * 16), BLK, 0, stream>>>(
        x, w[0], b[0], sw[0], sb[0], uflag16, opk16);

    // layer 2: K=13 dil=3 pool(3,1): Lin=482 Lconv=446 Lout=149
    {
        const int NLPG = (149 + 3) / 4;
        int nw = 128 * NLPG * 4;
        bconv_bit_kernel<13, 3, 3, 1, 4, 4><<<blocksForWaves(nw), BLK, 0, stream>>>(
            a1, wpk2, b[1], sw[1], sb[1], a2, 256, 482, 446, 149, NLPG, nw);
    }
    // layer 3: K=7 dil=2 pool(3,1): Lin=149 Lconv=137 Lout=46
    {
        const int NLPG = (46 + 3) / 4;
        int nw = 128 * NLPG * 4;
        bconv_bit_kernel<7, 2, 3, 1, 4, 4><<<blocksForWaves(nw), BLK, 0, stream>>>(
            a2, wpk3, b[2], sw[2], sb[2], a3, 256, 149, 137, 46, NLPG, nw);
    }
    // fused tail: layers 4,5,6 + fc1 + fc2
    tail_kernel<<<dim3(128), BLK, 0, stream>>>(
        a3, wpk4, wpk5, wpk6,
        b[3], sw[3], sb[3], b[4], sw[4], sb[4], b[5], sw[5], sb[5],
        fw1pk, fsw1, fsb1, fpk2, fsw2, fsb2, out);
}

// Round 12
// 356.860 us; speedup vs baseline: 2.3273x; 1.1893x over previous
//
#include <hip/hip_runtime.h>
#include <cstdint>
#include <cstddef>

typedef unsigned long long u64;
typedef uint32_t u32;
typedef uint16_t u16;
typedef uint8_t u8;

// ---------------------------------------------------------------------------
// Binary AlexNet-1D. bq(w)=0.1*sign(w), bact(x)=sign(x). All binary layers are
// exact integer XNOR-popcount + f64 affine epilogue. Activations bitpacked as
// [N][L][C/64] u64. Conv sum = CIN*K - 2*popc(a^w); maxpool (stride==kernel,
// scale 0.1>0) commutes with the affine map, so pool the integer sums.
// Layer 1 (real f32 input): register-tiled f32 FMA pass. Thread owns 16 ch x
// 5 conv positions (= one pool window; acc[16][5] in VGPRs). waves_per_eu(1,3)
// targets the middle regime: VGPR cap ~170 (acc tile resident, no AGPR
// round-trips) while allowing up to 3 waves/SIMD to hide LDS latency.
// Weights +-1.0f in LDS (uniform-address float4 broadcast), x in LDS tile.
// Near-zero outputs (|v| < margin) recomputed in f64 by a fixup kernel ->
// sign decisions stay f64-exact.
// Layers 4..6 + fc1 + fc2 fused into one block-per-sample kernel (LDS).
// ---------------------------------------------------------------------------

#define CONV1_MARGIN 1e-4f

// -------------------- merged weight packing --------------------
// packs w[Cout][CIN][K] float -> wpk[K][Cout][CIN/64]; fc layers use K=1.
// Trailing blocks (wid >= totalWaves) handle misc packing: fc1 sign masks and
// layer-1 sign floats (branch is wave-aligned, ballot stays coherent).
struct PackJob { const float* src; u64* dst; int Cout, CIN, K, waveBase; };
struct PackJobs {
    PackJob j[6]; int totalWaves;
    const float* fw1; u32* fw1pk;        // [512][32] -> u32[512]
    const float* w1;  float* sgnf;       // [256][69] -> [16][69][16] +-1.0f
};

__global__ void pack_all_kernel(PackJobs P)
{
    int gtid = blockIdx.x * blockDim.x + threadIdx.x;
    int wid = gtid >> 6, lane = gtid & 63;
    if (wid < P.totalWaves) {
        int jj = 0;
        #pragma unroll
        for (int i = 1; i < 6; ++i) if (wid >= P.j[i].waveBase) jj = i;
        PackJob job = P.j[jj];
        int lw = wid - job.waveBase;
        int W = job.CIN >> 6;
        int wg = lw % W;
        int co = (lw / W) % job.Cout;
        int k  = lw / (W * job.Cout);
        int ci = wg * 64 + lane;
        bool sg = job.src[((size_t)co * job.CIN + ci) * job.K + k] >= 0.0f;
        u64 word = __ballot(sg);
        if (lane == 0) job.dst[lw] = word;
        return;
    }
    int idx = gtid - P.totalWaves * 64;
    if (idx < 512) {
        u32 wd = 0;
        #pragma unroll
        for (int i = 0; i < 32; ++i) wd |= (u32)(P.fw1[idx * 32 + i] >= 0.0f) << i;
        P.fw1pk[idx] = wd;
    }
    int j = idx - 512;
    if (j >= 0 && j < 256 * 69) {
        int i = j % 69, co = j / 69;
        P.sgnf[(size_t)(co >> 4) * 69 * 16 + i * 16 + (co & 15)] =
            (P.w1[(size_t)co * 69 + i] >= 0.0f) ? 1.0f : -1.0f;
    }
}

// -------------------- layer 1 --------------------
// grid (n=128, bl=2, chunk=16), block 256. Thread tid -> pooled output
// lp = 256*bl + tid for 16 channels [16*chunk, 16*chunk+16).
// conv positions l = 5*lp-2+j, j=0..4 (one pool window, thread-local max).
// x tile + 16-channel weight tile in LDS; acc[16][5] in VGPRs.
__global__ __launch_bounds__(256)
__attribute__((amdgpu_waves_per_eu(1, 3)))
void conv1_pass1_kernel(
    const float* __restrict__ x, const float* __restrict__ sgnf,
    const float* __restrict__ b, const float* __restrict__ sw,
    const float* __restrict__ sb,
    u16* __restrict__ opk16, u16* __restrict__ uflag16)
{
    __shared__ float xt[3 * 1440];
    __shared__ float wt[69 * 16];
    const int Lin = 2560, Lconv = 2406;
    int n = blockIdx.x, bl = blockIdx.y, chunk = blockIdx.z;
    int tid = threadIdx.x;
    int base = 1280 * bl - 2;

    // stage x tile (source index clamped; clamped values are only ever read
    // by conv positions that the pooling max later excludes)
    const float* xb = x + (size_t)n * 3 * Lin;
    for (int idx = tid; idx < 3 * 1440; idx += 256) {
        int ci = idx / 1440, rel = idx - ci * 1440;
        int src = min(max(base + rel, 0), Lin - 1);
        xt[idx] = xb[ci * Lin + src];
    }
    // stage weight signs (+-1.0f), layout already [i][c] for this chunk
    for (int idx = tid; idx < 69 * 16; idx += 256)
        wt[idx] = sgnf[(size_t)chunk * 69 * 16 + idx];
    __syncthreads();

    float acc[16][5];
    #pragma unroll
    for (int c = 0; c < 16; ++c)
        #pragma unroll
        for (int j = 0; j < 5; ++j) acc[c][j] = 0.0f;

    const float* xrow = xt + 5 * tid;
    #pragma unroll 1
    for (int ci = 0; ci < 3; ++ci) {
        #pragma unroll
        for (int kk = 0; kk < 23; ++kk) {
            float xv[5];
            #pragma unroll
            for (int j = 0; j < 5; ++j)
                xv[j] = xrow[ci * 1440 + 7 * kk + j];
            const float4* wrow = (const float4*)(wt + (ci * 23 + kk) * 16);
            #pragma unroll
            for (int g = 0; g < 4; ++g) {
                float4 wv = wrow[g];
                #pragma unroll
                for (int j = 0; j < 5; ++j) {
                    acc[g * 4 + 0][j] = fmaf(xv[j], wv.x, acc[g * 4 + 0][j]);
                    acc[g * 4 + 1][j] = fmaf(xv[j], wv.y, acc[g * 4 + 1][j]);
                    acc[g * 4 + 2][j] = fmaf(xv[j], wv.z, acc[g * 4 + 2][j]);
                    acc[g * 4 + 3][j] = fmaf(xv[j], wv.w, acc[g * 4 + 3][j]);
                }
            }
        }
    }

    int lp = 256 * bl + tid;
    if (lp < 482) {
        u32 bits = 0, uncs = 0;
        #pragma unroll
        for (int c = 0; c < 16; ++c) {
            int co = chunk * 16 + c;
            float best = -1e30f;
            #pragma unroll
            for (int j = 0; j < 5; ++j) {
                int l = 5 * lp - 2 + j;
                if (l >= 0 && l < Lconv) best = fmaxf(best, acc[c][j]);
            }
            float v = ((sw[co] >= 0.0f) ? 0.1f : -0.1f) * (0.1f * best + b[co]) + sb[co];
            bits |= (v >= 0.0f ? 1u : 0u) << c;
            uncs |= (fabsf(v) < CONV1_MARGIN ? 1u : 0u) << c;
        }
        size_t widx = ((size_t)n * 482 + lp) * 16 + chunk;
        opk16[widx] = (u16)bits;
        uflag16[widx] = (u16)uncs;
    }
}

// Fixup: thread per packed u16 word; recompute flagged channels in f64.
__global__ void conv1_fixup_kernel(const float* __restrict__ x,
                                   const float* __restrict__ w1,
                                   const float* __restrict__ b,
                                   const float* __restrict__ sw,
                                   const float* __restrict__ sb,
                                   const u16* __restrict__ uflag16,
                                   u16* __restrict__ opk16)
{
    int idx = blockIdx.x * blockDim.x + threadIdx.x;
    if (idx >= 128 * 482 * 16) return;
    u32 f = uflag16[idx];
    if (f == 0) return;
    int chunk = idx & 15;
    int lp = (idx >> 4) % 482;
    int n = idx / (16 * 482);
    u32 word = opk16[idx];
    const float* xb = x + (size_t)n * 3 * 2560;
    while (f) {
        int c = __ffs(f) - 1;
        f &= f - 1;
        int co = chunk * 16 + c;
        const float* wp = w1 + (size_t)co * 69;
        double best = -1e300;
        for (int t = 0; t < 5; ++t) {
            int gl = 5 * lp - 2 + t;
            if (gl < 0 || gl >= 2406) continue;
            double s = 0.0;
            #pragma unroll
            for (int ci = 0; ci < 3; ++ci) {
                const float* xp = xb + ci * 2560 + gl;
                const float* wq = wp + ci * 23;
                #pragma unroll
                for (int kk = 0; kk < 23; ++kk) {
                    double xv = (double)xp[kk * 7];
                    s += (wq[kk] >= 0.0f) ? xv : -xv;
                }
            }
            best = fmax(best, s);
        }
        double v = ((sw[co] >= 0.0f) ? 0.1 : -0.1) * (0.1 * best + (double)b[co]) + (double)sb[co];
        u32 bit = (v >= 0.0) ? 1u : 0u;
        word = (word & ~(1u << c)) | (bit << c);
    }
    opk16[idx] = word;
}

// -------------------- binary conv layers 2,3 (XNOR-popcount) ---------------
// One wave = 64 output channels x LPW pooled positions at one (n,og).
template<int K, int DIL, int PK, int PP, int W, int LPW>
__global__ void bconv_bit_kernel(const u64* __restrict__ apk,  // [N][Lin][W]
                                 const u64* __restrict__ wpk,  // [K][Cout][W]
                                 const float* __restrict__ b,
                                 const float* __restrict__ sw,
                                 const float* __restrict__ sb,
                                 u64* __restrict__ opk,        // [N][Lout][Cout/64]
                                 int Cout, int Lin, int Lconv, int Lout,
                                 int NLPG, int nwaves)
{
    int wid = __builtin_amdgcn_readfirstlane(
        (int)(blockIdx.x * (blockDim.x >> 6)) + (int)(threadIdx.x >> 6));
    int lane = threadIdx.x & 63;
    if (wid >= nwaves) return;
    int WOUT = Cout >> 6;
    int og = wid % WOUT;
    int lpg = (wid / WOUT) % NLPG;
    int n  = wid / (WOUT * NLPG);
    int lp0 = lpg * LPW;
    int co = og * 64 + lane;

    const u64* ab = apk + (size_t)n * Lin * W;
    int cnt[LPW][PK];
    #pragma unroll
    for (int j = 0; j < LPW; ++j)
        #pragma unroll
        for (int t = 0; t < PK; ++t) cnt[j][t] = 0;

    #pragma unroll
    for (int k = 0; k < K; ++k) {
        u64 ww[W];
        #pragma unroll
        for (int w = 0; w < W; ++w)
            ww[w] = wpk[((size_t)k * Cout + co) * W + w];
        #pragma unroll
        for (int j = 0; j < LPW; ++j) {
            int lp = lp0 + j;
            #pragma unroll
            for (int t = 0; t < PK; ++t) {
                int l = lp * PK - PP + t;
                if (lp >= Lout || l < 0 || l >= Lconv) continue;
                const u64* ap = ab + (size_t)(l + k * DIL) * W;
                #pragma unroll
                for (int w = 0; w < W; ++w)
                    cnt[j][t] += __popcll(ap[w] ^ ww[w]);
            }
        }
    }
    const int CINK = W * 64 * K;
    #pragma unroll
    for (int j = 0; j < LPW; ++j) {
        int lp = lp0 + j;
        int best = -2147483647;
        #pragma unroll
        for (int t = 0; t < PK; ++t) {
            int l = lp * PK - PP + t;
            if (l < 0 || l >= Lconv) continue;
            int ksum = CINK - 2 * cnt[j][t];
            best = (ksum > best) ? ksum : best;
        }
        bool bit = false;
        if (lp < Lout) {
            double conv = 0.1 * (double)best + (double)b[co];
            double v = ((sw[co] >= 0.0f) ? 0.1 : -0.1) * conv + (double)sb[co];
            bit = (v >= 0.0);
        }
        u64 word = __ballot(bit);
        if (lp < Lout && lane == 0)
            opk[((size_t)n * Lout + lp) * WOUT + og] = word;
    }
}

// -------------------- fused tail: layers 4,5,6 + fc1 + fc2 -----------------
// One block (256 threads) per sample n; intermediates live in LDS.
__global__ __launch_bounds__(256) void tail_kernel(
    const u64* __restrict__ a3,      // [128][46][4]
    const u64* __restrict__ wpk4,    // [5][256][4]
    const u64* __restrict__ wpk5,    // [5][256][4]
    const u64* __restrict__ wpk6,    // [3][8][4]
    const float* __restrict__ b4, const float* __restrict__ sw4, const float* __restrict__ sb4,
    const float* __restrict__ b5, const float* __restrict__ sw5, const float* __restrict__ sb5,
    const float* __restrict__ b6, const float* __restrict__ sw6, const float* __restrict__ sb6,
    const u32* __restrict__ fw1pk,   // [512]
    const float* __restrict__ fsw1, const float* __restrict__ fsb1,
    const u64* __restrict__ fpk2,    // [1000][8]
    const float* __restrict__ fsw2, const float* __restrict__ fsb2,
    float* __restrict__ out)         // [128][1000]
{
    __shared__ u64 sA[46 * 4];   // layer-4 input
    __shared__ u64 sB[42 * 4];   // layer-4 output
    __shared__ u64 sC[13 * 4];   // layer-5 output
    __shared__ u32 sA6;          // layer-6 output, 32 bits (bit = co*4+lp)
    __shared__ u64 sH[8];        // fc1 output, 512 bits
    int n = blockIdx.x, tid = threadIdx.x, lane = tid & 63, wv = tid >> 6;

    for (int i = tid; i < 46 * 4; i += 256) sA[i] = a3[(size_t)n * 46 * 4 + i];
    __syncthreads();

    // ---- layer 4: K=5, dil=1, no pool, Lconv=Lout=42, thread = channel ----
    {
        u64 ww[5][4];
        #pragma unroll
        for (int k = 0; k < 5; ++k)
            #pragma unroll
            for (int w = 0; w < 4; ++w)
                ww[k][w] = wpk4[((size_t)k * 256 + tid) * 4 + w];
        double bc = b4[tid];
        double swc = (sw4[tid] >= 0.0f) ? 0.1 : -0.1;
        double sbc = sb4[tid];
        for (int lp = 0; lp < 42; ++lp) {
            int cnt = 0;
            #pragma unroll
            for (int k = 0; k < 5; ++k)
                #pragma unroll
                for (int w = 0; w < 4; ++w)
                    cnt += __popcll(sA[(lp + k) * 4 + w] ^ ww[k][w]);
            int ksum = 256 * 5 - 2 * cnt;
            double v = swc * (0.1 * ksum + bc) + sbc;
            u64 word = __ballot(v >= 0.0);
            if (lane == 0) sB[lp * 4 + wv] = word;
        }
    }
    __syncthreads();

    // ---- layer 5: K=5, pool(3,1), Lconv=38, Lout=13, thread = channel ----
    {
        u64 ww[5][4];
        #pragma unroll
        for (int k = 0; k < 5; ++k)
            #pragma unroll
            for (int w = 0; w < 4; ++w)
                ww[k][w] = wpk5[((size_t)k * 256 + tid) * 4 + w];
        double bc = b5[tid];
        double swc = (sw5[tid] >= 0.0f) ? 0.1 : -0.1;
        double sbc = sb5[tid];
        for (int lp = 0; lp < 13; ++lp) {
            int best = -2147483647;
            #pragma unroll
            for (int t = 0; t < 3; ++t) {
                int l = 3 * lp - 1 + t;
                if (l < 0 || l >= 38) continue;
                int cnt = 0;
                #pragma unroll
                for (int k = 0; k < 5; ++k)
                    #pragma unroll
                    for (int w = 0; w < 4; ++w)
                        cnt += __popcll(sB[(l + k) * 4 + w] ^ ww[k][w]);
                int ksum = 256 * 5 - 2 * cnt;
                best = (ksum > best) ? ksum : best;
            }
            double v = swc * (0.1 * best + bc) + sbc;
            u64 word = __ballot(v >= 0.0);
            if (lane == 0) sC[lp * 4 + wv] = word;
        }
    }
    __syncthreads();

    // ---- layer 6: Cout=8, K=3, pool(3,1), Lconv=11, Lout=4 ----
    if (tid < 32) {
        int co = tid >> 2, lp = tid & 3;
        int best = -2147483647;
        for (int t = 0; t < 3; ++t) {
            int l = 3 * lp - 1 + t;
            if (l < 0 || l >= 11) continue;
            int cnt = 0;
            #pragma unroll
            for (int k = 0; k < 3; ++k)
                #pragma unroll
                for (int w = 0; w < 4; ++w)
                    cnt += __popcll(sC[(l + k) * 4 + w] ^ wpk6[((size_t)k * 8 + co) * 4 + w]);
            int ksum = 256 * 3 - 2 * cnt;
            best = (ksum > best) ? ksum : best;
        }
        double v = ((sw6[co] >= 0.0f) ? 0.1 : -0.1) * (0.1 * best + (double)b6[co]) + (double)sb6[co];
        u64 word = __ballot(v >= 0.0);   // bit index = tid = co*4+lp (reshape order)
        if (tid == 0) sA6 = (u32)word;
    }
    __syncthreads();

    // ---- fc1: 512 outputs, 32-bit xnor-popcount ----
    {
        u32 a6w = sA6;
        #pragma unroll
        for (int p = 0; p < 2; ++p) {
            int o = tid + p * 256;
            int k = 32 - 2 * __popc(a6w ^ fw1pk[o]);
            double v = ((fsw1[o] >= 0.0f) ? 0.1 : -0.1) * (0.1 * (double)k) + (double)fsb1[o];
            u64 word = __ballot(v >= 0.0);
            if (lane == 0) sH[p * 4 + wv] = word;
        }
    }
    __syncthreads();

    // ---- fc2: 1000 outputs, 512-bit xnor-popcount, f32 store ----
    {
        u64 h[8];
        #pragma unroll
        for (int w = 0; w < 8; ++w) h[w] = sH[w];
        #pragma unroll
        for (int p = 0; p < 4; ++p) {
            int o = tid + p * 256;
            if (o < 1000) {
                int cnt = 0;
                #pragma unroll
                for (int w = 0; w < 8; ++w)
                    cnt += __popcll(h[w] ^ fpk2[(size_t)o * 8 + w]);
                int k = 512 - 2 * cnt;
                double v = ((fsw2[o] >= 0.0f) ? 0.1 : -0.1) * (0.1 * (double)k) + (double)fsb2[o];
                out[(size_t)n * 1000 + o] = (float)v;
            }
        }
    }
}

extern "C" void kernel_launch(void* const* d_in, const int* in_sizes, int n_in,
                              void* d_out, int out_size, void* d_ws, size_t ws_size,
                              hipStream_t stream) {
    const float* x = (const float*)d_in[0];
    const float *w[6], *b[6], *sw[6], *sb[6];
    for (int i = 0; i < 6; ++i) {
        w[i]  = (const float*)d_in[1 + 4 * i];
        b[i]  = (const float*)d_in[2 + 4 * i];
        sw[i] = (const float*)d_in[3 + 4 * i];
        sb[i] = (const float*)d_in[4 + 4 * i];
    }
    const float* fw1  = (const float*)d_in[25];
    const float* fsw1 = (const float*)d_in[26];
    const float* fsb1 = (const float*)d_in[27];
    const float* fw2  = (const float*)d_in[28];
    const float* fsw2 = (const float*)d_in[29];
    const float* fsb2 = (const float*)d_in[30];
    float* out = (float*)d_out;
    (void)in_sizes; (void)n_in; (void)out_size; (void)ws_size;

    char* wsbase = (char*)d_ws;
    size_t off = 0;
    auto alloc = [&](size_t bytes) -> char* {
        char* p = wsbase + off;
        off = (off + bytes + 255) & ~(size_t)255;
        return p;
    };
    u64* wpk2 = (u64*)alloc((size_t)13 * 256 * 4 * 8);
    u64* wpk3 = (u64*)alloc((size_t)7 * 256 * 4 * 8);
    u64* wpk4 = (u64*)alloc((size_t)5 * 256 * 4 * 8);
    u64* wpk5 = (u64*)alloc((size_t)5 * 256 * 4 * 8);
    u64* wpk6 = (u64*)alloc((size_t)3 * 8 * 4 * 8);
    u64* fpk2 = (u64*)alloc((size_t)1000 * 8 * 8);
    u32* fw1pk = (u32*)alloc((size_t)512 * 4);
    float* sgnf = (float*)alloc((size_t)16 * 69 * 16 * 4);
    u16* uflag16 = (u16*)alloc((size_t)128 * 482 * 16 * 2);
    u64* a1   = (u64*)alloc((size_t)128 * 482 * 4 * 8);
    u64* a2   = (u64*)alloc((size_t)128 * 149 * 4 * 8);
    u64* a3   = (u64*)alloc((size_t)128 * 46 * 4 * 8);
    u16* opk16 = (u16*)a1;  // u16 word (co/16) aliases u64 word (co/64) bits

    const int BLK = 256;
    auto blocksForWaves = [](int nwaves) { return dim3((unsigned)((nwaves * 64 + 255) / 256)); };
    auto blocksForThreads = [](int n) { return dim3((unsigned)((n + 255) / 256)); };

    // merged weight packing (fc2 job expressed as K=1; misc packing appended
    // as extra blocks past the wave jobs)
    {
        PackJobs P;
        int base = 0;
        auto setJob = [&](int i, const float* src, u64* dst, int Cout, int CIN, int K) {
            P.j[i] = {src, dst, Cout, CIN, K, base};
            base += K * Cout * (CIN >> 6);
        };
        setJob(0, w[1], wpk2, 256, 256, 13);
        setJob(1, w[2], wpk3, 256, 256, 7);
        setJob(2, w[3], wpk4, 256, 256, 5);
        setJob(3, w[4], wpk5, 256, 256, 5);
        setJob(4, w[5], wpk6, 8, 256, 3);
        setJob(5, fw2, fpk2, 1000, 512, 1);
        P.totalWaves = base;
        P.fw1 = fw1; P.fw1pk = fw1pk; P.w1 = w[0]; P.sgnf = sgnf;
        int totalThreads = base * 64 + 512 + 256 * 69;
        pack_all_kernel<<<blocksForThreads(totalThreads), BLK, 0, stream>>>(P);
    }

    // layer 1: register-tiled f32 pass + f64 fixup of near-zero outputs
    conv1_pass1_kernel<<<dim3(128, 2, 16), BLK, 0, stream>>>(
        x, sgnf, b[0], sw[0], sb[0], opk16, uflag16);
    conv1_fixup_kernel<<<blocksForThreads(128 * 482 * 16), BLK, 0, stream>>>(
        x, w[0], b[0], sw[0], sb[0], uflag16, opk16);

    // layer 2: K=13 dil=3 pool(3,1): Lin=482 Lconv=446 Lout=149
    {
        const int NLPG = (149 + 3) / 4;
        int nw = 128 * NLPG * 4;
        bconv_bit_kernel<13, 3, 3, 1, 4, 4><<<blocksForWaves(nw), BLK, 0, stream>>>(
            a1, wpk2, b[1], sw[1], sb[1], a2, 256, 482, 446, 149, NLPG, nw);
    }
    // layer 3: K=7 dil=2 pool(3,1): Lin=149 Lconv=137 Lout=46
    {
        const int NLPG = (46 + 3) / 4;
        int nw = 128 * NLPG * 4;
        bconv_bit_kernel<7, 2, 3, 1, 4, 4><<<blocksForWaves(nw), BLK, 0, stream>>>(
            a2, wpk3, b[2], sw[2], sb[2], a3, 256, 149, 137, 46, NLPG, nw);
    }
    // fused tail: layers 4,5,6 + fc1 + fc2
    tail_kernel<<<dim3(128), BLK, 0, stream>>>(
        a3, wpk4, wpk5, wpk6,
        b[3], sw[3], sb[3], b[4], sw[4], sb[4], b[5], sw[5], sb[5],
        fw1pk, fsw1, fsb1, fpk2, fsw2, fsb2, out);
}

// Round 13
// 353.825 us; speedup vs baseline: 2.3473x; 1.0086x over previous
//
#include <hip/hip_runtime.h>
#include <cstdint>
#include <cstddef>

typedef unsigned long long u64;
typedef uint32_t u32;
typedef uint16_t u16;
typedef uint8_t u8;
typedef float v2f __attribute__((ext_vector_type(2)));

// ---------------------------------------------------------------------------
// Binary AlexNet-1D. bq(w)=0.1*sign(w), bact(x)=sign(x). All binary layers are
// exact integer XNOR-popcount + f64 affine epilogue. Activations bitpacked as
// [N][L][C/64] u64. Conv sum = CIN*K - 2*popc(a^w); maxpool (stride==kernel,
// scale 0.1>0) commutes with the affine map, so pool the integer sums.
// Layer 1 (real f32 input): f32 FMA pass with PACKED math — thread owns 8 ch
// x 5 conv positions; positions paired into <2 x float> so the compiler emits
// v_pk_fma_f32 (2 MACs/inst), cutting issue slots ~2x vs scalar fmaf.
// acc = 40 regs (16 v2f + 8 f); waves_per_eu(1,6) gives ~85-VGPR budget so
// the tile stays arch-resident. Near-zero outputs (|v| < margin) recomputed
// in f64 by a fixup kernel -> sign decisions stay f64-exact.
// Layers 4..6 + fc1 + fc2 fused into one block-per-sample kernel (LDS).
// ---------------------------------------------------------------------------

#define CONV1_MARGIN 1e-4f

// -------------------- merged weight packing --------------------
// packs w[Cout][CIN][K] float -> wpk[K][Cout][CIN/64]; fc layers use K=1.
// Trailing blocks (wid >= totalWaves) handle misc packing: fc1 sign masks and
// layer-1 sign floats (branch is wave-aligned, ballot stays coherent).
struct PackJob { const float* src; u64* dst; int Cout, CIN, K, waveBase; };
struct PackJobs {
    PackJob j[6]; int totalWaves;
    const float* fw1; u32* fw1pk;        // [512][32] -> u32[512]
    const float* w1;  float* sgnf;       // [256][69] -> [32][69][8] +-1.0f
};

__global__ void pack_all_kernel(PackJobs P)
{
    int gtid = blockIdx.x * blockDim.x + threadIdx.x;
    int wid = gtid >> 6, lane = gtid & 63;
    if (wid < P.totalWaves) {
        int jj = 0;
        #pragma unroll
        for (int i = 1; i < 6; ++i) if (wid >= P.j[i].waveBase) jj = i;
        PackJob job = P.j[jj];
        int lw = wid - job.waveBase;
        int W = job.CIN >> 6;
        int wg = lw % W;
        int co = (lw / W) % job.Cout;
        int k  = lw / (W * job.Cout);
        int ci = wg * 64 + lane;
        bool sg = job.src[((size_t)co * job.CIN + ci) * job.K + k] >= 0.0f;
        u64 word = __ballot(sg);
        if (lane == 0) job.dst[lw] = word;
        return;
    }
    int idx = gtid - P.totalWaves * 64;
    if (idx < 512) {
        u32 wd = 0;
        #pragma unroll
        for (int i = 0; i < 32; ++i) wd |= (u32)(P.fw1[idx * 32 + i] >= 0.0f) << i;
        P.fw1pk[idx] = wd;
    }
    int j = idx - 512;
    if (j >= 0 && j < 256 * 69) {
        int i = j % 69, co = j / 69;
        P.sgnf[(size_t)(co >> 3) * 69 * 8 + i * 8 + (co & 7)] =
            (P.w1[(size_t)co * 69 + i] >= 0.0f) ? 1.0f : -1.0f;
    }
}

// -------------------- layer 1 --------------------
// grid (n=128, bl=2, chunk=32), block 256. Thread tid -> pooled output
// lp = 256*bl + tid for 8 channels [8*chunk, 8*chunk+8).
// conv positions l = 5*lp-2+j, j=0..4 (one pool window, thread-local max),
// positions paired (0,1),(2,3),(4) for v_pk_fma_f32.
__global__ __launch_bounds__(256)
__attribute__((amdgpu_waves_per_eu(1, 6)))
void conv1_pass1_kernel(
    const float* __restrict__ x, const float* __restrict__ sgnf,
    const float* __restrict__ b, const float* __restrict__ sw,
    const float* __restrict__ sb,
    u8* __restrict__ opk8, u8* __restrict__ uflag8)
{
    __shared__ float xt[3 * 1440];
    __shared__ float wt[69 * 8];
    const int Lin = 2560, Lconv = 2406;
    int n = blockIdx.x, bl = blockIdx.y, chunk = blockIdx.z;
    int tid = threadIdx.x;
    int base = 1280 * bl - 2;

    // stage x tile (source index clamped; clamped values are only ever read
    // by conv positions that the pooling max later excludes)
    const float* xb = x + (size_t)n * 3 * Lin;
    for (int idx = tid; idx < 3 * 1440; idx += 256) {
        int ci = idx / 1440, rel = idx - ci * 1440;
        int src = min(max(base + rel, 0), Lin - 1);
        xt[idx] = xb[ci * Lin + src];
    }
    // stage weight signs (+-1.0f), layout already [i][c] for this chunk
    for (int idx = tid; idx < 69 * 8; idx += 256)
        wt[idx] = sgnf[(size_t)chunk * 69 * 8 + idx];
    __syncthreads();

    v2f acc01[8], acc23[8];
    float acc4[8];
    #pragma unroll
    for (int c = 0; c < 8; ++c) {
        acc01[c] = (v2f){0.0f, 0.0f};
        acc23[c] = (v2f){0.0f, 0.0f};
        acc4[c] = 0.0f;
    }

    const float* xrow = xt + 5 * tid;
    #pragma unroll 1
    for (int ci = 0; ci < 3; ++ci) {
        #pragma unroll
        for (int kk = 0; kk < 23; ++kk) {
            const float* xp = xrow + ci * 1440 + 7 * kk;
            v2f x01 = {xp[0], xp[1]};
            v2f x23 = {xp[2], xp[3]};
            float x4 = xp[4];
            const float4* wrow = (const float4*)(wt + (ci * 23 + kk) * 8);
            float4 w0 = wrow[0], w1 = wrow[1];
            float wv[8] = {w0.x, w0.y, w0.z, w0.w, w1.x, w1.y, w1.z, w1.w};
            #pragma unroll
            for (int c = 0; c < 8; ++c) {
                v2f wp = {wv[c], wv[c]};
                acc01[c] = x01 * wp + acc01[c];   // v_pk_fma_f32
                acc23[c] = x23 * wp + acc23[c];   // v_pk_fma_f32
                acc4[c] = fmaf(x4, wv[c], acc4[c]);
            }
        }
    }

    int lp = 256 * bl + tid;
    if (lp < 482) {
        u32 bits = 0, uncs = 0;
        int l0 = 5 * lp - 2;
        #pragma unroll
        for (int c = 0; c < 8; ++c) {
            int co = chunk * 8 + c;
            float best = -1e30f;
            float av[5] = {acc01[c].x, acc01[c].y, acc23[c].x, acc23[c].y, acc4[c]};
            #pragma unroll
            for (int j = 0; j < 5; ++j) {
                int l = l0 + j;
                if (l >= 0 && l < Lconv) best = fmaxf(best, av[j]);
            }
            float v = ((sw[co] >= 0.0f) ? 0.1f : -0.1f) * (0.1f * best + b[co]) + sb[co];
            bits |= (v >= 0.0f ? 1u : 0u) << c;
            uncs |= (fabsf(v) < CONV1_MARGIN ? 1u : 0u) << c;
        }
        // byte `chunk` of the [N][L][4]u64 packed layout = channels 8chunk..+7
        size_t bidx = ((size_t)n * 482 + lp) * 32 + chunk;
        opk8[bidx] = (u8)bits;
        uflag8[bidx] = (u8)uncs;
    }
}

// Fixup: thread per packed u8 word; recompute flagged channels in f64.
__global__ void conv1_fixup_kernel(const float* __restrict__ x,
                                   const float* __restrict__ w1,
                                   const float* __restrict__ b,
                                   const float* __restrict__ sw,
                                   const float* __restrict__ sb,
                                   const u8* __restrict__ uflag8,
                                   u8* __restrict__ opk8)
{
    int idx = blockIdx.x * blockDim.x + threadIdx.x;
    if (idx >= 128 * 482 * 32) return;
    u32 f = uflag8[idx];
    if (f == 0) return;
    int chunk = idx & 31;
    int lp = (idx >> 5) % 482;
    int n = idx / (32 * 482);
    u32 word = opk8[idx];
    const float* xb = x + (size_t)n * 3 * 2560;
    while (f) {
        int c = __ffs(f) - 1;
        f &= f - 1;
        int co = chunk * 8 + c;
        const float* wp = w1 + (size_t)co * 69;
        double best = -1e300;
        for (int t = 0; t < 5; ++t) {
            int gl = 5 * lp - 2 + t;
            if (gl < 0 || gl >= 2406) continue;
            double s = 0.0;
            #pragma unroll
            for (int ci = 0; ci < 3; ++ci) {
                const float* xp = xb + ci * 2560 + gl;
                const float* wq = wp + ci * 23;
                #pragma unroll
                for (int kk = 0; kk < 23; ++kk) {
                    double xv = (double)xp[kk * 7];
                    s += (wq[kk] >= 0.0f) ? xv : -xv;
                }
            }
            best = fmax(best, s);
        }
        double v = ((sw[co] >= 0.0f) ? 0.1 : -0.1) * (0.1 * best + (double)b[co]) + (double)sb[co];
        u32 bit = (v >= 0.0) ? 1u : 0u;
        word = (word & ~(1u << c)) | (bit << c);
    }
    opk8[idx] = (u8)word;
}

// -------------------- binary conv layers 2,3 (XNOR-popcount) ---------------
// One wave = 64 output channels x LPW pooled positions at one (n,og).
template<int K, int DIL, int PK, int PP, int W, int LPW>
__global__ void bconv_bit_kernel(const u64* __restrict__ apk,  // [N][Lin][W]
                                 const u64* __restrict__ wpk,  // [K][Cout][W]
                                 const float* __restrict__ b,
                                 const float* __restrict__ sw,
                                 const float* __restrict__ sb,
                                 u64* __restrict__ opk,        // [N][Lout][Cout/64]
                                 int Cout, int Lin, int Lconv, int Lout,
                                 int NLPG, int nwaves)
{
    int wid = __builtin_amdgcn_readfirstlane(
        (int)(blockIdx.x * (blockDim.x >> 6)) + (int)(threadIdx.x >> 6));
    int lane = threadIdx.x & 63;
    if (wid >= nwaves) return;
    int WOUT = Cout >> 6;
    int og = wid % WOUT;
    int lpg = (wid / WOUT) % NLPG;
    int n  = wid / (WOUT * NLPG);
    int lp0 = lpg * LPW;
    int co = og * 64 + lane;

    const u64* ab = apk + (size_t)n * Lin * W;
    int cnt[LPW][PK];
    #pragma unroll
    for (int j = 0; j < LPW; ++j)
        #pragma unroll
        for (int t = 0; t < PK; ++t) cnt[j][t] = 0;

    #pragma unroll
    for (int k = 0; k < K; ++k) {
        u64 ww[W];
        #pragma unroll
        for (int w = 0; w < W; ++w)
            ww[w] = wpk[((size_t)k * Cout + co) * W + w];
        #pragma unroll
        for (int j = 0; j < LPW; ++j) {
            int lp = lp0 + j;
            #pragma unroll
            for (int t = 0; t < PK; ++t) {
                int l = lp * PK - PP + t;
                if (lp >= Lout || l < 0 || l >= Lconv) continue;
                const u64* ap = ab + (size_t)(l + k * DIL) * W;
                #pragma unroll
                for (int w = 0; w < W; ++w)
                    cnt[j][t] += __popcll(ap[w] ^ ww[w]);
            }
        }
    }
    const int CINK = W * 64 * K;
    #pragma unroll
    for (int j = 0; j < LPW; ++j) {
        int lp = lp0 + j;
        int best = -2147483647;
        #pragma unroll
        for (int t = 0; t < PK; ++t) {
            int l = lp * PK - PP + t;
            if (l < 0 || l >= Lconv) continue;
            int ksum = CINK - 2 * cnt[j][t];
            best = (ksum > best) ? ksum : best;
        }
        bool bit = false;
        if (lp < Lout) {
            double conv = 0.1 * (double)best + (double)b[co];
            double v = ((sw[co] >= 0.0f) ? 0.1 : -0.1) * conv + (double)sb[co];
            bit = (v >= 0.0);
        }
        u64 word = __ballot(bit);
        if (lp < Lout && lane == 0)
            opk[((size_t)n * Lout + lp) * WOUT + og] = word;
    }
}

// -------------------- fused tail: layers 4,5,6 + fc1 + fc2 -----------------
// One block (256 threads) per sample n; intermediates live in LDS.
__global__ __launch_bounds__(256) void tail_kernel(
    const u64* __restrict__ a3,      // [128][46][4]
    const u64* __restrict__ wpk4,    // [5][256][4]
    const u64* __restrict__ wpk5,    // [5][256][4]
    const u64* __restrict__ wpk6,    // [3][8][4]
    const float* __restrict__ b4, const float* __restrict__ sw4, const float* __restrict__ sb4,
    const float* __restrict__ b5, const float* __restrict__ sw5, const float* __restrict__ sb5,
    const float* __restrict__ b6, const float* __restrict__ sw6, const float* __restrict__ sb6,
    const u32* __restrict__ fw1pk,   // [512]
    const float* __restrict__ fsw1, const float* __restrict__ fsb1,
    const u64* __restrict__ fpk2,    // [1000][8]
    const float* __restrict__ fsw2, const float* __restrict__ fsb2,
    float* __restrict__ out)         // [128][1000]
{
    __shared__ u64 sA[46 * 4];   // layer-4 input
    __shared__ u64 sB[42 * 4];   // layer-4 output
    __shared__ u64 sC[13 * 4];   // layer-5 output
    __shared__ u32 sA6;          // layer-6 output, 32 bits (bit = co*4+lp)
    __shared__ u64 sH[8];        // fc1 output, 512 bits
    int n = blockIdx.x, tid = threadIdx.x, lane = tid & 63, wv = tid >> 6;

    for (int i = tid; i < 46 * 4; i += 256) sA[i] = a3[(size_t)n * 46 * 4 + i];
    __syncthreads();

    // ---- layer 4: K=5, dil=1, no pool, Lconv=Lout=42, thread = channel ----
    {
        u64 ww[5][4];
        #pragma unroll
        for (int k = 0; k < 5; ++k)
            #pragma unroll
            for (int w = 0; w < 4; ++w)
                ww[k][w] = wpk4[((size_t)k * 256 + tid) * 4 + w];
        double bc = b4[tid];
        double swc = (sw4[tid] >= 0.0f) ? 0.1 : -0.1;
        double sbc = sb4[tid];
        for (int lp = 0; lp < 42; ++lp) {
            int cnt = 0;
            #pragma unroll
            for (int k = 0; k < 5; ++k)
                #pragma unroll
                for (int w = 0; w < 4; ++w)
                    cnt += __popcll(sA[(lp + k) * 4 + w] ^ ww[k][w]);
            int ksum = 256 * 5 - 2 * cnt;
            double v = swc * (0.1 * ksum + bc) + sbc;
            u64 word = __ballot(v >= 0.0);
            if (lane == 0) sB[lp * 4 + wv] = word;
        }
    }
    __syncthreads();

    // ---- layer 5: K=5, pool(3,1), Lconv=38, Lout=13, thread = channel ----
    {
        u64 ww[5][4];
        #pragma unroll
        for (int k = 0; k < 5; ++k)
            #pragma unroll
            for (int w = 0; w < 4; ++w)
                ww[k][w] = wpk5[((size_t)k * 256 + tid) * 4 + w];
        double bc = b5[tid];
        double swc = (sw5[tid] >= 0.0f) ? 0.1 : -0.1;
        double sbc = sb5[tid];
        for (int lp = 0; lp < 13; ++lp) {
            int best = -2147483647;
            #pragma unroll
            for (int t = 0; t < 3; ++t) {
                int l = 3 * lp - 1 + t;
                if (l < 0 || l >= 38) continue;
                int cnt = 0;
                #pragma unroll
                for (int k = 0; k < 5; ++k)
                    #pragma unroll
                    for (int w = 0; w < 4; ++w)
                        cnt += __popcll(sB[(l + k) * 4 + w] ^ ww[k][w]);
                int ksum = 256 * 5 - 2 * cnt;
                best = (ksum > best) ? ksum : best;
            }
            double v = swc * (0.1 * best + bc) + sbc;
            u64 word = __ballot(v >= 0.0);
            if (lane == 0) sC[lp * 4 + wv] = word;
        }
    }
    __syncthreads();

    // ---- layer 6: Cout=8, K=3, pool(3,1), Lconv=11, Lout=4 ----
    if (tid < 32) {
        int co = tid >> 2, lp = tid & 3;
        int best = -2147483647;
        for (int t = 0; t < 3; ++t) {
            int l = 3 * lp - 1 + t;
            if (l < 0 || l >= 11) continue;
            int cnt = 0;
            #pragma unroll
            for (int k = 0; k < 3; ++k)
                #pragma unroll
                for (int w = 0; w < 4; ++w)
                    cnt += __popcll(sC[(l + k) * 4 + w] ^ wpk6[((size_t)k * 8 + co) * 4 + w]);
            int ksum = 256 * 3 - 2 * cnt;
            best = (ksum > best) ? ksum : best;
        }
        double v = ((sw6[co] >= 0.0f) ? 0.1 : -0.1) * (0.1 * best + (double)b6[co]) + (double)sb6[co];
        u64 word = __ballot(v >= 0.0);   // bit index = tid = co*4+lp (reshape order)
        if (tid == 0) sA6 = (u32)word;
    }
    __syncthreads();

    // ---- fc1: 512 outputs, 32-bit xnor-popcount ----
    {
        u32 a6w = sA6;
        #pragma unroll
        for (int p = 0; p < 2; ++p) {
            int o = tid + p * 256;
            int k = 32 - 2 * __popc(a6w ^ fw1pk[o]);
            double v = ((fsw1[o] >= 0.0f) ? 0.1 : -0.1) * (0.1 * (double)k) + (double)fsb1[o];
            u64 word = __ballot(v >= 0.0);
            if (lane == 0) sH[p * 4 + wv] = word;
        }
    }
    __syncthreads();

    // ---- fc2: 1000 outputs, 512-bit xnor-popcount, f32 store ----
    {
        u64 h[8];
        #pragma unroll
        for (int w = 0; w < 8; ++w) h[w] = sH[w];
        #pragma unroll
        for (int p = 0; p < 4; ++p) {
            int o = tid + p * 256;
            if (o < 1000) {
                int cnt = 0;
                #pragma unroll
                for (int w = 0; w < 8; ++w)
                    cnt += __popcll(h[w] ^ fpk2[(size_t)o * 8 + w]);
                int k = 512 - 2 * cnt;
                double v = ((fsw2[o] >= 0.0f) ? 0.1 : -0.1) * (0.1 * (double)k) + (double)fsb2[o];
                out[(size_t)n * 1000 + o] = (float)v;
            }
        }
    }
}

extern "C" void kernel_launch(void* const* d_in, const int* in_sizes, int n_in,
                              void* d_out, int out_size, void* d_ws, size_t ws_size,
                              hipStream_t stream) {
    const float* x = (const float*)d_in[0];
    const float *w[6], *b[6], *sw[6], *sb[6];
    for (int i = 0; i < 6; ++i) {
        w[i]  = (const float*)d_in[1 + 4 * i];
        b[i]  = (const float*)d_in[2 + 4 * i];
        sw[i] = (const float*)d_in[3 + 4 * i];
        sb[i] = (const float*)d_in[4 + 4 * i];
    }
    const float* fw1  = (const float*)d_in[25];
    const float* fsw1 = (const float*)d_in[26];
    const float* fsb1 = (const float*)d_in[27];
    const float* fw2  = (const float*)d_in[28];
    const float* fsw2 = (const float*)d_in[29];
    const float* fsb2 = (const float*)d_in[30];
    float* out = (float*)d_out;
    (void)in_sizes; (void)n_in; (void)out_size; (void)ws_size;

    char* wsbase = (char*)d_ws;
    size_t off = 0;
    auto alloc = [&](size_t bytes) -> char* {
        char* p = wsbase + off;
        off = (off + bytes + 255) & ~(size_t)255;
        return p;
    };
    u64* wpk2 = (u64*)alloc((size_t)13 * 256 * 4 * 8);
    u64* wpk3 = (u64*)alloc((size_t)7 * 256 * 4 * 8);
    u64* wpk4 = (u64*)alloc((size_t)5 * 256 * 4 * 8);
    u64* wpk5 = (u64*)alloc((size_t)5 * 256 * 4 * 8);
    u64* wpk6 = (u64*)alloc((size_t)3 * 8 * 4 * 8);
    u64* fpk2 = (u64*)alloc((size_t)1000 * 8 * 8);
    u32* fw1pk = (u32*)alloc((size_t)512 * 4);
    float* sgnf = (float*)alloc((size_t)32 * 69 * 8 * 4);
    u8* uflag8 = (u8*)alloc((size_t)128 * 482 * 32);
    u64* a1   = (u64*)alloc((size_t)128 * 482 * 4 * 8);
    u64* a2   = (u64*)alloc((size_t)128 * 149 * 4 * 8);
    u64* a3   = (u64*)alloc((size_t)128 * 46 * 4 * 8);
    u8* opk8 = (u8*)a1;  // byte `chunk` of u64 word og=chunk/8 = ch 8chunk..+7

    const int BLK = 256;
    auto blocksForWaves = [](int nwaves) { return dim3((unsigned)((nwaves * 64 + 255) / 256)); };
    auto blocksForThreads = [](int n) { return dim3((unsigned)((n + 255) / 256)); };

    // merged weight packing (fc2 job expressed as K=1; misc packing appended
    // as extra blocks past the wave jobs)
    {
        PackJobs P;
        int base = 0;
        auto setJob = [&](int i, const float* src, u64* dst, int Cout, int CIN, int K) {
            P.j[i] = {src, dst, Cout, CIN, K, base};
            base += K * Cout * (CIN >> 6);
        };
        setJob(0, w[1], wpk2, 256, 256, 13);
        setJob(1, w[2], wpk3, 256, 256, 7);
        setJob(2, w[3], wpk4, 256, 256, 5);
        setJob(3, w[4], wpk5, 256, 256, 5);
        setJob(4, w[5], wpk6, 8, 256, 3);
        setJob(5, fw2, fpk2, 1000, 512, 1);
        P.totalWaves = base;
        P.fw1 = fw1; P.fw1pk = fw1pk; P.w1 = w[0]; P.sgnf = sgnf;
        int totalThreads = base * 64 + 512 + 256 * 69;
        pack_all_kernel<<<blocksForThreads(totalThreads), BLK, 0, stream>>>(P);
    }

    // layer 1: packed-FMA f32 pass + f64 fixup of near-zero outputs
    conv1_pass1_kernel<<<dim3(128, 2, 32), BLK, 0, stream>>>(
        x, sgnf, b[0], sw[0], sb[0], opk8, uflag8);
    conv1_fixup_kernel<<<blocksForThreads(128 * 482 * 32), BLK, 0, stream>>>(
        x, w[0], b[0], sw[0], sb[0], uflag8, opk8);

    // layer 2: K=13 dil=3 pool(3,1): Lin=482 Lconv=446 Lout=149
    {
        const int NLPG = (149 + 3) / 4;
        int nw = 128 * NLPG * 4;
        bconv_bit_kernel<13, 3, 3, 1, 4, 4><<<blocksForWaves(nw), BLK, 0, stream>>>(
            a1, wpk2, b[1], sw[1], sb[1], a2, 256, 482, 446, 149, NLPG, nw);
    }
    // layer 3: K=7 dil=2 pool(3,1): Lin=149 Lconv=137 Lout=46
    {
        const int NLPG = (46 + 3) / 4;
        int nw = 128 * NLPG * 4;
        bconv_bit_kernel<7, 2, 3, 1, 4, 4><<<blocksForWaves(nw), BLK, 0, stream>>>(
            a2, wpk3, b[2], sw[2], sb[2], a3, 256, 149, 137, 46, NLPG, nw);
    }
    // fused tail: layers 4,5,6 + fc1 + fc2
    tail_kernel<<<dim3(128), BLK, 0, stream>>>(
        a3, wpk4, wpk5, wpk6,
        b[3], sw[3], sb[3], b[4], sw[4], sb[4], b[5], sw[5], sb[5],
        fw1pk, fsw1, fsb1, fpk2, fsw2, fsb2, out);
}

// Round 15
// 349.235 us; speedup vs baseline: 2.3781x; 1.0131x over previous
//
#include <hip/hip_runtime.h>
#include <cstdint>
#include <cstddef>

typedef unsigned long long u64;
typedef uint32_t u32;
typedef uint16_t u16;
typedef uint8_t u8;
typedef __attribute__((ext_vector_type(8))) short bf16x8;
typedef __attribute__((ext_vector_type(4))) float f32x4;

// ---------------------------------------------------------------------------
// Binary AlexNet-1D. bq(w)=0.1*sign(w), bact(x)=sign(x). All binary layers are
// exact integer XNOR-popcount + f64 affine epilogue. Activations bitpacked as
// [N][L][C/64] u64. Conv sum = CIN*K - 2*popc(a^w); maxpool (stride==kernel,
// scale 0.1>0) commutes with the affine map, so pool the integer sums.
// Layer 1 (real f32 input): bf16x2 split-precision MFMA GEMM.
//   x = hi(bf16) + lo(bf16 of residual)  (captures x to ~2^-18)
//   conv = [W | W] (K=192, +-1 bf16, 0-padded 69..95) . [X_hi ; X_lo]
//   -> f32 conv sums, worst-case error on v ~3e-6 << 1e-4 margin; near-zero
//   outputs recomputed in f64 by the fixup kernel -> signs stay f64-exact.
// Pooling: monotone u32-mapped f32 max via LDS atomicMax (ds_max_u32).
// Layers 4..6 + fc1 + fc2 fused into one block-per-sample kernel (LDS).
// ---------------------------------------------------------------------------

#define CONV1_MARGIN 1e-4f

// -------------------- merged weight packing --------------------
// packs w[Cout][CIN][K] float -> wpk[K][Cout][CIN/64]; fc layers use K=1.
// Trailing threads: fc1 sign masks (u32[512]) + layer-1 bf16 weights
// wbf[256 co][192 k] (+-1.0 bf16 for k%96 < 69, else 0).
struct PackJob { const float* src; u64* dst; int Cout, CIN, K, waveBase; };
struct PackJobs {
    PackJob j[6]; int totalWaves;
    const float* fw1; u32* fw1pk;
    const float* w1;  u16* wbf;
};

__global__ void pack_all_kernel(PackJobs P)
{
    int gtid = blockIdx.x * blockDim.x + threadIdx.x;
    int wid = gtid >> 6, lane = gtid & 63;
    if (wid < P.totalWaves) {
        int jj = 0;
        #pragma unroll
        for (int i = 1; i < 6; ++i) if (wid >= P.j[i].waveBase) jj = i;
        PackJob job = P.j[jj];
        int lw = wid - job.waveBase;
        int W = job.CIN >> 6;
        int wg = lw % W;
        int co = (lw / W) % job.Cout;
        int k  = lw / (W * job.Cout);
        int ci = wg * 64 + lane;
        bool sg = job.src[((size_t)co * job.CIN + ci) * job.K + k] >= 0.0f;
        u64 word = __ballot(sg);
        if (lane == 0) job.dst[lw] = word;
        return;
    }
    int idx = gtid - P.totalWaves * 64;
    if (idx < 512) {
        u32 wd = 0;
        #pragma unroll
        for (int i = 0; i < 32; ++i) wd |= (u32)(P.fw1[idx * 32 + i] >= 0.0f) << i;
        P.fw1pk[idx] = wd;
    }
    int j = idx - 512;
    if (j >= 0 && j < 256 * 192) {
        int co = j / 192, k = j - co * 192;
        int i = (k >= 96) ? (k - 96) : k;
        u16 val = 0;
        if (i < 69)
            val = (P.w1[(size_t)co * 69 + i] >= 0.0f) ? (u16)0x3F80 : (u16)0xBF80;
        P.wbf[(size_t)co * 192 + k] = val;
    }
}

// -------------------- layer 1: split-bf16 MFMA GEMM --------------------
// grid (n=128, T=31 lp-strips of 16, ch=2 co-halves of 128), block 256 = 4 waves.
// Conv positions l in [80T-2, 80T+78): 5 pos-tiles of 16. Per pos-tile:
// stage X2[192 k][16 pos] (hi+lo bf16) into LDS as [pos][k]; wave w computes
// co = 128ch + 32w + {0..31} via 2 co-tiles x 6 K-steps of mfma 16x16x32 bf16;
// C lanes (col=lane&15 -> pos, row=(lane>>4)*4+r -> co) atomicMax into the
// pooled slot (monotone u32 map). Epilogue: unmap, affine, sign, ballot-pack.
__global__ __launch_bounds__(256) void conv1_mfma_kernel(
    const float* __restrict__ x, const u16* __restrict__ wbf,
    const float* __restrict__ b, const float* __restrict__ sw,
    const float* __restrict__ sb,
    u64* __restrict__ opk64, u64* __restrict__ uflag64)
{
    __shared__ u16 Xb[16 * 208];          // [pos][k 0..191], row pad 208
    __shared__ unsigned poolm[128 * 16];  // mapped-f32 pooled max
    const int Lconv = 2406, Lin = 2560;
    int n = blockIdx.x, T = blockIdx.y, ch = blockIdx.z;
    int tid = threadIdx.x, lane = tid & 63, w = tid >> 6;
    int l0 = 80 * T - 2;

    for (int i = tid; i < 128 * 16; i += 256) poolm[i] = 0u;

    // A-frags (weights), resident across the block (AGPR-friendly: MFMA reads
    // A directly from the unified file, no copy cost).
    bf16x8 afr[2][6];
    {
        int cobase = 128 * ch + 32 * w;
        #pragma unroll
        for (int m = 0; m < 2; ++m) {
            const u16* wp = wbf + (size_t)(cobase + m * 16 + (lane & 15)) * 192
                           + (lane >> 4) * 8;
            #pragma unroll
            for (int s = 0; s < 6; ++s)
                afr[m][s] = *(const bf16x8*)(wp + s * 32);
        }
    }

    const float* xb = x + (size_t)n * 3 * Lin;

    for (int j = 0; j < 5; ++j) {
        __syncthreads();   // pool-init / previous tile's B-reads complete
        #pragma unroll
        for (int e = 0; e < 6; ++e) {
            int elem = tid + 256 * e;          // 0..1535
            int p = elem & 15, i = elem >> 4;  // i in 0..95
            u16 hi = 0, lo = 0;
            if (i < 69) {
                int ci = (i < 23) ? 0 : ((i < 46) ? 1 : 2);
                int kk = i - 23 * ci;
                int l = l0 + 16 * j + p + 7 * kk;   // x-index, range [-2, Lin+..)
                // clamp to the x array; clamped values only ever feed conv
                // positions outside [0, Lconv) which the pooling guard drops
                int c = min(max(l, 0), Lin - 1);
                float xv = xb[ci * Lin + c];
                u32 ub = __float_as_uint(xv);
                u32 h = (ub + 0x7FFFu + ((ub >> 16) & 1u)) >> 16;   // RNE bf16
                hi = (u16)h;
                float rem = xv - __uint_as_float(h << 16);
                u32 ur = __float_as_uint(rem);
                lo = (u16)((ur + 0x7FFFu + ((ur >> 16) & 1u)) >> 16);
            }
            Xb[p * 208 + i] = hi;        // k = i       (hi half)
            Xb[p * 208 + 96 + i] = lo;   // k = 96 + i  (lo half)
        }
        __syncthreads();

        f32x4 acc0 = {0.0f, 0.0f, 0.0f, 0.0f};
        f32x4 acc1 = {0.0f, 0.0f, 0.0f, 0.0f};
        const u16* brow = &Xb[(lane & 15) * 208 + (lane >> 4) * 8];
        #pragma unroll
        for (int s = 0; s < 6; ++s) {
            bf16x8 bf = *(const bf16x8*)(brow + s * 32);
            acc0 = __builtin_amdgcn_mfma_f32_16x16x32_bf16(afr[0][s], bf, acc0, 0, 0, 0);
            acc1 = __builtin_amdgcn_mfma_f32_16x16x32_bf16(afr[1][s], bf, acc1, 0, 0, 0);
        }

        int p = lane & 15;
        int q = 16 * j + p;
        int l = l0 + q;
        if (l >= 0 && l < Lconv) {
            int lp_loc = q / 5;
            #pragma unroll
            for (int m = 0; m < 2; ++m) {
                #pragma unroll
                for (int r = 0; r < 4; ++r) {
                    float v = (m == 0) ? acc0[r] : acc1[r];
                    int co_loc = 32 * w + 16 * m + (lane >> 4) * 4 + r;
                    u32 bits = __float_as_uint(v);
                    u32 mv = (bits & 0x80000000u) ? ~bits : (bits | 0x80000000u);
                    atomicMax(&poolm[co_loc * 16 + lp_loc], mv);
                }
            }
        }
    }
    __syncthreads();

    // pooled -> affine -> sign -> pack (wave = 64 consecutive co = one u64 word)
    {
        int co_loc = tid & 127;
        int half = tid >> 7;
        int co = 128 * ch + co_loc;
        float bc = b[co];
        float swc = (sw[co] >= 0.0f) ? 0.1f : -0.1f;
        float sbc = sb[co];
        #pragma unroll
        for (int k = 0; k < 8; ++k) {
            int lp_loc = half * 8 + k;
            int lp = 16 * T + lp_loc;
            bool bit = false, unc = false;
            if (lp < 482) {
                u32 mv = poolm[co_loc * 16 + lp_loc];
                u32 bits = (mv & 0x80000000u) ? (mv & 0x7FFFFFFFu) : ~mv;
                float best = __uint_as_float(bits);
                float v = swc * (0.1f * best + bc) + sbc;
                bit = (v >= 0.0f);
                unc = (fabsf(v) < CONV1_MARGIN);
            }
            u64 wb = __ballot(bit);
            u64 wu = __ballot(unc);
            if (lp < 482 && lane == 0) {
                size_t widx = ((size_t)n * 482 + lp) * 4 + (ch * 2 + (co_loc >> 6));
                opk64[widx] = wb;
                uflag64[widx] = wu;
            }
        }
    }
}

// Fixup: thread per packed u64 word; recompute flagged channels in f64.
__global__ void conv1_fixup_kernel(const float* __restrict__ x,
                                   const float* __restrict__ w1,
                                   const float* __restrict__ b,
                                   const float* __restrict__ sw,
                                   const float* __restrict__ sb,
                                   const u64* __restrict__ uflag64,
                                   u64* __restrict__ opk64)
{
    int idx = blockIdx.x * blockDim.x + threadIdx.x;
    if (idx >= 128 * 482 * 4) return;
    u64 f = uflag64[idx];
    if (f == 0) return;
    int og = idx & 3;
    int lp = (idx >> 2) % 482;
    int n = idx / (4 * 482);
    u64 word = opk64[idx];
    const float* xb = x + (size_t)n * 3 * 2560;
    while (f) {
        int c = __ffsll(f) - 1;
        f &= f - 1;
        int co = og * 64 + c;
        const float* wp = w1 + (size_t)co * 69;
        double best = -1e300;
        for (int t = 0; t < 5; ++t) {
            int gl = 5 * lp - 2 + t;
            if (gl < 0 || gl >= 2406) continue;
            double s = 0.0;
            #pragma unroll
            for (int ci = 0; ci < 3; ++ci) {
                const float* xp = xb + ci * 2560 + gl;
                const float* wq = wp + ci * 23;
                #pragma unroll
                for (int kk = 0; kk < 23; ++kk) {
                    double xv = (double)xp[kk * 7];
                    s += (wq[kk] >= 0.0f) ? xv : -xv;
                }
            }
            best = fmax(best, s);
        }
        double v = ((sw[co] >= 0.0f) ? 0.1 : -0.1) * (0.1 * best + (double)b[co]) + (double)sb[co];
        u64 bit = (v >= 0.0) ? 1ull : 0ull;
        word = (word & ~(1ull << c)) | (bit << c);
    }
    opk64[idx] = word;
}

// -------------------- binary conv layers 2,3 (XNOR-popcount) ---------------
template<int K, int DIL, int PK, int PP, int W, int LPW>
__global__ void bconv_bit_kernel(const u64* __restrict__ apk,
                                 const u64* __restrict__ wpk,
                                 const float* __restrict__ b,
                                 const float* __restrict__ sw,
                                 const float* __restrict__ sb,
                                 u64* __restrict__ opk,
                                 int Cout, int Lin, int Lconv, int Lout,
                                 int NLPG, int nwaves)
{
    int wid = __builtin_amdgcn_readfirstlane(
        (int)(blockIdx.x * (blockDim.x >> 6)) + (int)(threadIdx.x >> 6));
    int lane = threadIdx.x & 63;
    if (wid >= nwaves) return;
    int WOUT = Cout >> 6;
    int og = wid % WOUT;
    int lpg = (wid / WOUT) % NLPG;
    int n  = wid / (WOUT * NLPG);
    int lp0 = lpg * LPW;
    int co = og * 64 + lane;

    const u64* ab = apk + (size_t)n * Lin * W;
    int cnt[LPW][PK];
    #pragma unroll
    for (int j = 0; j < LPW; ++j)
        #pragma unroll
        for (int t = 0; t < PK; ++t) cnt[j][t] = 0;

    #pragma unroll
    for (int k = 0; k < K; ++k) {
        u64 ww[W];
        #pragma unroll
        for (int w = 0; w < W; ++w)
            ww[w] = wpk[((size_t)k * Cout + co) * W + w];
        #pragma unroll
        for (int j = 0; j < LPW; ++j) {
            int lp = lp0 + j;
            #pragma unroll
            for (int t = 0; t < PK; ++t) {
                int l = lp * PK - PP + t;
                if (lp >= Lout || l < 0 || l >= Lconv) continue;
                const u64* ap = ab + (size_t)(l + k * DIL) * W;
                #pragma unroll
                for (int w = 0; w < W; ++w)
                    cnt[j][t] += __popcll(ap[w] ^ ww[w]);
            }
        }
    }
    const int CINK = W * 64 * K;
    #pragma unroll
    for (int j = 0; j < LPW; ++j) {
        int lp = lp0 + j;
        int best = -2147483647;
        #pragma unroll
        for (int t = 0; t < PK; ++t) {
            int l = lp * PK - PP + t;
            if (l < 0 || l >= Lconv) continue;
            int ksum = CINK - 2 * cnt[j][t];
            best = (ksum > best) ? ksum : best;
        }
        bool bit = false;
        if (lp < Lout) {
            double conv = 0.1 * (double)best + (double)b[co];
            double v = ((sw[co] >= 0.0f) ? 0.1 : -0.1) * conv + (double)sb[co];
            bit = (v >= 0.0);
        }
        u64 word = __ballot(bit);
        if (lp < Lout && lane == 0)
            opk[((size_t)n * Lout + lp) * WOUT + og] = word;
    }
}

// -------------------- fused tail: layers 4,5,6 + fc1 + fc2 -----------------
__global__ __launch_bounds__(256) void tail_kernel(
    const u64* __restrict__ a3,
    const u64* __restrict__ wpk4,
    const u64* __restrict__ wpk5,
    const u64* __restrict__ wpk6,
    const float* __restrict__ b4, const float* __restrict__ sw4, const float* __restrict__ sb4,
    const float* __restrict__ b5, const float* __restrict__ sw5, const float* __restrict__ sb5,
    const float* __restrict__ b6, const float* __restrict__ sw6, const float* __restrict__ sb6,
    const u32* __restrict__ fw1pk,
    const float* __restrict__ fsw1, const float* __restrict__ fsb1,
    const u64* __restrict__ fpk2,
    const float* __restrict__ fsw2, const float* __restrict__ fsb2,
    float* __restrict__ out)
{
    __shared__ u64 sA[46 * 4];
    __shared__ u64 sB[42 * 4];
    __shared__ u64 sC[13 * 4];
    __shared__ u32 sA6;
    __shared__ u64 sH[8];
    int n = blockIdx.x, tid = threadIdx.x, lane = tid & 63, wv = tid >> 6;

    for (int i = tid; i < 46 * 4; i += 256) sA[i] = a3[(size_t)n * 46 * 4 + i];
    __syncthreads();

    {
        u64 ww[5][4];
        #pragma unroll
        for (int k = 0; k < 5; ++k)
            #pragma unroll
            for (int w = 0; w < 4; ++w)
                ww[k][w] = wpk4[((size_t)k * 256 + tid) * 4 + w];
        double bc = b4[tid];
        double swc = (sw4[tid] >= 0.0f) ? 0.1 : -0.1;
        double sbc = sb4[tid];
        for (int lp = 0; lp < 42; ++lp) {
            int cnt = 0;
            #pragma unroll
            for (int k = 0; k < 5; ++k)
                #pragma unroll
                for (int w = 0; w < 4; ++w)
                    cnt += __popcll(sA[(lp + k) * 4 + w] ^ ww[k][w]);
            int ksum = 256 * 5 - 2 * cnt;
            double v = swc * (0.1 * ksum + bc) + sbc;
            u64 word = __ballot(v >= 0.0);
            if (lane == 0) sB[lp * 4 + wv] = word;
        }
    }
    __syncthreads();

    {
        u64 ww[5][4];
        #pragma unroll
        for (int k = 0; k < 5; ++k)
            #pragma unroll
            for (int w = 0; w < 4; ++w)
                ww[k][w] = wpk5[((size_t)k * 256 + tid) * 4 + w];
        double bc = b5[tid];
        double swc = (sw5[tid] >= 0.0f) ? 0.1 : -0.1;
        double sbc = sb5[tid];
        for (int lp = 0; lp < 13; ++lp) {
            int best = -2147483647;
            #pragma unroll
            for (int t = 0; t < 3; ++t) {
                int l = 3 * lp - 1 + t;
                if (l < 0 || l >= 38) continue;
                int cnt = 0;
                #pragma unroll
                for (int k = 0; k < 5; ++k)
                    #pragma unroll
                    for (int w = 0; w < 4; ++w)
                        cnt += __popcll(sB[(l + k) * 4 + w] ^ ww[k][w]);
                int ksum = 256 * 5 - 2 * cnt;
                best = (ksum > best) ? ksum : best;
            }
            double v = swc * (0.1 * best + bc) + sbc;
            u64 word = __ballot(v >= 0.0);
            if (lane == 0) sC[lp * 4 + wv] = word;
        }
    }
    __syncthreads();

    if (tid < 32) {
        int co = tid >> 2, lp = tid & 3;
        int best = -2147483647;
        for (int t = 0; t < 3; ++t) {
            int l = 3 * lp - 1 + t;
            if (l < 0 || l >= 11) continue;
            int cnt = 0;
            #pragma unroll
            for (int k = 0; k < 3; ++k)
                #pragma unroll
                for (int w = 0; w < 4; ++w)
                    cnt += __popcll(sC[(l + k) * 4 + w] ^ wpk6[((size_t)k * 8 + co) * 4 + w]);
            int ksum = 256 * 3 - 2 * cnt;
            best = (ksum > best) ? ksum : best;
        }
        double v = ((sw6[co] >= 0.0f) ? 0.1 : -0.1) * (0.1 * best + (double)b6[co]) + (double)sb6[co];
        u64 word = __ballot(v >= 0.0);
        if (tid == 0) sA6 = (u32)word;
    }
    __syncthreads();

    {
        u32 a6w = sA6;
        #pragma unroll
        for (int p = 0; p < 2; ++p) {
            int o = tid + p * 256;
            int k = 32 - 2 * __popc(a6w ^ fw1pk[o]);
            double v = ((fsw1[o] >= 0.0f) ? 0.1 : -0.1) * (0.1 * (double)k) + (double)fsb1[o];
            u64 word = __ballot(v >= 0.0);
            if (lane == 0) sH[p * 4 + wv] = word;
        }
    }
    __syncthreads();

    {
        u64 h[8];
        #pragma unroll
        for (int w = 0; w < 8; ++w) h[w] = sH[w];
        #pragma unroll
        for (int p = 0; p < 4; ++p) {
            int o = tid + p * 256;
            if (o < 1000) {
                int cnt = 0;
                #pragma unroll
                for (int w = 0; w < 8; ++w)
                    cnt += __popcll(h[w] ^ fpk2[(size_t)o * 8 + w]);
                int k = 512 - 2 * cnt;
                double v = ((fsw2[o] >= 0.0f) ? 0.1 : -0.1) * (0.1 * (double)k) + (double)fsb2[o];
                out[(size_t)n * 1000 + o] = (float)v;
            }
        }
    }
}

extern "C" void kernel_launch(void* const* d_in, const int* in_sizes, int n_in,
                              void* d_out, int out_size, void* d_ws, size_t ws_size,
                              hipStream_t stream) {
    const float* x = (const float*)d_in[0];
    const float *w[6], *b[6], *sw[6], *sb[6];
    for (int i = 0; i < 6; ++i) {
        w[i]  = (const float*)d_in[1 + 4 * i];
        b[i]  = (const float*)d_in[2 + 4 * i];
        sw[i] = (const float*)d_in[3 + 4 * i];
        sb[i] = (const float*)d_in[4 + 4 * i];
    }
    const float* fw1  = (const float*)d_in[25];
    const float* fsw1 = (const float*)d_in[26];
    const float* fsb1 = (const float*)d_in[27];
    const float* fw2  = (const float*)d_in[28];
    const float* fsw2 = (const float*)d_in[29];
    const float* fsb2 = (const float*)d_in[30];
    float* out = (float*)d_out;
    (void)in_sizes; (void)n_in; (void)out_size; (void)ws_size;

    char* wsbase = (char*)d_ws;
    size_t off = 0;
    auto alloc = [&](size_t bytes) -> char* {
        char* p = wsbase + off;
        off = (off + bytes + 255) & ~(size_t)255;
        return p;
    };
    u64* wpk2 = (u64*)alloc((size_t)13 * 256 * 4 * 8);
    u64* wpk3 = (u64*)alloc((size_t)7 * 256 * 4 * 8);
    u64* wpk4 = (u64*)alloc((size_t)5 * 256 * 4 * 8);
    u64* wpk5 = (u64*)alloc((size_t)5 * 256 * 4 * 8);
    u64* wpk6 = (u64*)alloc((size_t)3 * 8 * 4 * 8);
    u64* fpk2 = (u64*)alloc((size_t)1000 * 8 * 8);
    u32* fw1pk = (u32*)alloc((size_t)512 * 4);
    u16* wbf = (u16*)alloc((size_t)256 * 192 * 2);
    u64* uflag64 = (u64*)alloc((size_t)128 * 482 * 4 * 8);
    u64* a1   = (u64*)alloc((size_t)128 * 482 * 4 * 8);
    u64* a2   = (u64*)alloc((size_t)128 * 149 * 4 * 8);
    u64* a3   = (u64*)alloc((size_t)128 * 46 * 4 * 8);

    const int BLK = 256;
    auto blocksForWaves = [](int nwaves) { return dim3((unsigned)((nwaves * 64 + 255) / 256)); };
    auto blocksForThreads = [](int n) { return dim3((unsigned)((n + 255) / 256)); };

    // merged weight packing (+ misc tail: fc1 masks, layer-1 bf16 weights)
    {
        PackJobs P;
        int base = 0;
        auto setJob = [&](int i, const float* src, u64* dst, int Cout, int CIN, int K) {
            P.j[i] = {src, dst, Cout, CIN, K, base};
            base += K * Cout * (CIN >> 6);
        };
        setJob(0, w[1], wpk2, 256, 256, 13);
        setJob(1, w[2], wpk3, 256, 256, 7);
        setJob(2, w[3], wpk4, 256, 256, 5);
        setJob(3, w[4], wpk5, 256, 256, 5);
        setJob(4, w[5], wpk6, 8, 256, 3);
        setJob(5, fw2, fpk2, 1000, 512, 1);
        P.totalWaves = base;
        P.fw1 = fw1; P.fw1pk = fw1pk; P.w1 = w[0]; P.wbf = wbf;
        int totalThreads = base * 64 + 512 + 256 * 192;
        pack_all_kernel<<<blocksForThreads(totalThreads), BLK, 0, stream>>>(P);
    }

    // layer 1: split-bf16 MFMA GEMM + f64 fixup of near-zero outputs
    conv1_mfma_kernel<<<dim3(128, 31, 2), BLK, 0, stream>>>(
        x, wbf, b[0], sw[0], sb[0], a1, uflag64);
    conv1_fixup_kernel<<<blocksForThreads(128 * 482 * 4), BLK, 0, stream>>>(
        x, w[0], b[0], sw[0], sb[0], uflag64, a1);

    // layer 2: K=13 dil=3 pool(3,1): Lin=482 Lconv=446 Lout=149
    {
        const int NLPG = (149 + 3) / 4;
        int nw = 128 * NLPG * 4;
        bconv_bit_kernel<13, 3, 3, 1, 4, 4><<<blocksForWaves(nw), BLK, 0, stream>>>(
            a1, wpk2, b[1], sw[1], sb[1], a2, 256, 482, 446, 149, NLPG, nw);
    }
    // layer 3: K=7 dil=2 pool(3,1): Lin=149 Lconv=137 Lout=46
    {
        const int NLPG = (46 + 3) / 4;
        int nw = 128 * NLPG * 4;
        bconv_bit_kernel<7, 2, 3, 1, 4, 4><<<blocksForWaves(nw), BLK, 0, stream>>>(
            a2, wpk3, b[2], sw[2], sb[2], a3, 256, 149, 137, 46, NLPG, nw);
    }
    // fused tail: layers 4,5,6 + fc1 + fc2
    tail_kernel<<<dim3(128), BLK, 0, stream>>>(
        a3, wpk4, wpk5, wpk6,
        b[3], sw[3], sb[3], b[4], sw[4], sb[4], b[5], sw[5], sb[5],
        fw1pk, fsw1, fsb1, fpk2, fsw2, fsb2, out);
}

// Round 16
// 314.653 us; speedup vs baseline: 2.6395x; 1.1099x over previous
//
#include <hip/hip_runtime.h>
#include <cstdint>
#include <cstddef>

typedef unsigned long long u64;
typedef uint32_t u32;
typedef uint16_t u16;
typedef uint8_t u8;
typedef __attribute__((ext_vector_type(8))) short bf16x8;
typedef __attribute__((ext_vector_type(4))) float f32x4;

// ---------------------------------------------------------------------------
// Binary AlexNet-1D. bq(w)=0.1*sign(w), bact(x)=sign(x). All binary layers are
// exact integer XNOR-popcount + f64 affine epilogue. Activations bitpacked as
// [N][L][C/64] u64. Conv sum = CIN*K - 2*popc(a^w); maxpool (stride==kernel,
// scale 0.1>0) commutes with the affine map, so pool the integer sums.
// Layer 1 (real f32 input): bf16x2 split-precision MFMA GEMM.
//   x = hi(bf16) + lo(bf16 of residual); conv = [W|W](K=192) . [X_hi;X_lo]
//   f32 sums, worst-case error ~3e-6 << 1e-4 margin; near-zero outputs are
//   recomputed in f64 by the fixup kernel -> signs stay f64-exact.
//   v2: x converted once/block into packed xhl; Xb staged as u32 pairs
//   (2-way banks); pooling via raw f32 stores to poolf[co][81] + guarded
//   epilogue (replaces 16-way-conflicted LDS atomicMax).
// Layers 4..6 + fc1 + fc2 fused into one block-per-sample kernel (LDS).
// ---------------------------------------------------------------------------

#define CONV1_MARGIN 1e-4f

// -------------------- merged weight packing --------------------
struct PackJob { const float* src; u64* dst; int Cout, CIN, K, waveBase; };
struct PackJobs {
    PackJob j[6]; int totalWaves;
    const float* fw1; u32* fw1pk;
    const float* w1;  u16* wbf;
};

__global__ void pack_all_kernel(PackJobs P)
{
    int gtid = blockIdx.x * blockDim.x + threadIdx.x;
    int wid = gtid >> 6, lane = gtid & 63;
    if (wid < P.totalWaves) {
        int jj = 0;
        #pragma unroll
        for (int i = 1; i < 6; ++i) if (wid >= P.j[i].waveBase) jj = i;
        PackJob job = P.j[jj];
        int lw = wid - job.waveBase;
        int W = job.CIN >> 6;
        int wg = lw % W;
        int co = (lw / W) % job.Cout;
        int k  = lw / (W * job.Cout);
        int ci = wg * 64 + lane;
        bool sg = job.src[((size_t)co * job.CIN + ci) * job.K + k] >= 0.0f;
        u64 word = __ballot(sg);
        if (lane == 0) job.dst[lw] = word;
        return;
    }
    int idx = gtid - P.totalWaves * 64;
    if (idx < 512) {
        u32 wd = 0;
        #pragma unroll
        for (int i = 0; i < 32; ++i) wd |= (u32)(P.fw1[idx * 32 + i] >= 0.0f) << i;
        P.fw1pk[idx] = wd;
    }
    int j = idx - 512;
    if (j >= 0 && j < 256 * 192) {
        int co = j / 192, k = j - co * 192;
        int i = (k >= 96) ? (k - 96) : k;
        u16 val = 0;
        if (i < 69)
            val = (P.w1[(size_t)co * 69 + i] >= 0.0f) ? (u16)0x3F80 : (u16)0xBF80;
        P.wbf[(size_t)co * 192 + k] = val;
    }
}

// -------------------- layer 1: split-bf16 MFMA GEMM (v2) --------------------
// grid (n=128, T=31 strips of 80 conv-pos = 16 lp, ch=2 co-halves), block 256.
// Phase 0: xhl[3][236] = packed (lo<<16|hi) bf16 pair per x sample, once.
// Per pos-tile j (5): stage Xb[16 pos][216 u16] via u32-pair LDS gather;
// 2 co-tiles x 6 K-steps of mfma 16x16x32; store raw sums to poolf[co][81].
// Epilogue: guarded 5-tap pool max, affine, sign, ballot-pack u64 words.
__global__ __launch_bounds__(256) void conv1_mfma_kernel(
    const float* __restrict__ x, const u16* __restrict__ wbf,
    const float* __restrict__ b, const float* __restrict__ sw,
    const float* __restrict__ sb,
    u64* __restrict__ opk64, u64* __restrict__ uflag64)
{
    __shared__ u32 xhl[3 * 236];       // (lo<<16)|hi per x sample of the strip
    __shared__ u32 Xb32[16 * 108];     // [pos][k-pair]; hi dwords 0..47, lo 48..95
    __shared__ float poolf[128 * 81];  // [co_loc][q] raw conv sums
    const int Lconv = 2406, Lin = 2560;
    int n = blockIdx.x, T = blockIdx.y, ch = blockIdx.z;
    int tid = threadIdx.x, lane = tid & 63, w = tid >> 6;
    int l0 = 80 * T - 2;

    // A-frags (weights), resident across the block
    bf16x8 afr[2][6];
    {
        int cobase = 128 * ch + 32 * w;
        #pragma unroll
        for (int m = 0; m < 2; ++m) {
            const u16* wp = wbf + (size_t)(cobase + m * 16 + (lane & 15)) * 192
                           + (lane >> 4) * 8;
            #pragma unroll
            for (int s = 0; s < 6; ++s)
                afr[m][s] = *(const bf16x8*)(wp + s * 32);
        }
    }

    // phase 0: convert strip's x to packed bf16 hi/lo, once
    const float* xb = x + (size_t)n * 3 * Lin;
    #pragma unroll
    for (int e = 0; e < 3; ++e) {
        int idx = tid + 256 * e;
        if (idx < 3 * 236) {
            int ci = idx / 236, lrel = idx - ci * 236;
            // clamp to x array; clamped values only feed conv positions
            // outside [0, Lconv), which the epilogue bounds-guard drops
            int l = min(max(l0 + lrel, 0), Lin - 1);
            float xv = xb[ci * Lin + l];
            u32 ub = __float_as_uint(xv);
            u32 h = (ub + 0x7FFFu + ((ub >> 16) & 1u)) >> 16;   // RNE bf16
            float rem = xv - __uint_as_float(h << 16);
            u32 ur = __float_as_uint(rem);
            u32 lo = (ur + 0x7FFFu + ((ur >> 16) & 1u)) >> 16;
            xhl[idx] = (h & 0xFFFFu) | (lo << 16);
        }
    }
    __syncthreads();

    for (int j = 0; j < 5; ++j) {
        if (j) __syncthreads();   // previous tile's B-reads complete
        // stage Xb: 768 (pos, k-pair) slots, u32 writes (2-way banks)
        #pragma unroll
        for (int e = 0; e < 3; ++e) {
            int s = tid + 256 * e;           // 0..767
            int p = s & 15, i2 = s >> 4;     // i2 in 0..47 -> taps 2i2, 2i2+1
            u32 hiw = 0, low = 0;
            #pragma unroll
            for (int t2 = 0; t2 < 2; ++t2) {
                int t = 2 * i2 + t2;
                if (t < 69) {
                    int ci = (t < 23) ? 0 : ((t < 46) ? 1 : 2);
                    int kk = t - 23 * ci;
                    u32 v = xhl[ci * 236 + 16 * j + p + 7 * kk];
                    hiw |= (v & 0xFFFFu) << (16 * t2);
                    low |= (v >> 16) << (16 * t2);
                }
            }
            Xb32[p * 108 + i2] = hiw;        // k = 2i2, 2i2+1   (hi half)
            Xb32[p * 108 + 48 + i2] = low;   // k = 96+2i2, +1   (lo half)
        }
        __syncthreads();

        f32x4 acc0 = {0.0f, 0.0f, 0.0f, 0.0f};
        f32x4 acc1 = {0.0f, 0.0f, 0.0f, 0.0f};
        const u16* brow = (const u16*)Xb32 + (lane & 15) * 216 + (lane >> 4) * 8;
        #pragma unroll
        for (int s = 0; s < 6; ++s) {
            bf16x8 bf = *(const bf16x8*)(brow + s * 32);
            acc0 = __builtin_amdgcn_mfma_f32_16x16x32_bf16(afr[0][s], bf, acc0, 0, 0, 0);
            acc1 = __builtin_amdgcn_mfma_f32_16x16x32_bf16(afr[1][s], bf, acc1, 0, 0, 0);
        }

        // raw stores (no atomics): poolf[co_loc][q], stride 81 (17co banks)
        int q = 16 * j + (lane & 15);
        #pragma unroll
        for (int m = 0; m < 2; ++m) {
            #pragma unroll
            for (int r = 0; r < 4; ++r) {
                float v = (m == 0) ? acc0[r] : acc1[r];
                int co_loc = 32 * w + 16 * m + (lane >> 4) * 4 + r;
                poolf[co_loc * 81 + q] = v;
            }
        }
    }
    __syncthreads();

    // epilogue: guarded pool + affine + sign + ballot-pack
    #pragma unroll
    for (int it = 0; it < 8; ++it) {
        int idx = tid + 256 * it;        // 0..2047
        int co_loc = idx & 127;
        int lp_loc = idx >> 7;           // 0..15 (wave-uniform)
        int lp = 16 * T + lp_loc;
        int co = 128 * ch + co_loc;
        bool bit = false, unc = false;
        if (lp < 482) {
            float best = -1e30f;
            #pragma unroll
            for (int t = 0; t < 5; ++t) {
                int q = 5 * lp_loc + t;
                int l = l0 + q;
                if (l >= 0 && l < Lconv)
                    best = fmaxf(best, poolf[co_loc * 81 + q]);
            }
            float v = ((sw[co] >= 0.0f) ? 0.1f : -0.1f) * (0.1f * best + b[co]) + sb[co];
            bit = (v >= 0.0f);
            unc = (fabsf(v) < CONV1_MARGIN);
        }
        u64 wb = __ballot(bit);
        u64 wu = __ballot(unc);
        if (lp < 482 && lane == 0) {
            size_t widx = ((size_t)n * 482 + lp) * 4 + (ch * 2 + (co_loc >> 6));
            opk64[widx] = wb;
            uflag64[widx] = wu;
        }
    }
}

// Fixup: thread per packed u64 word; recompute flagged channels in f64.
__global__ void conv1_fixup_kernel(const float* __restrict__ x,
                                   const float* __restrict__ w1,
                                   const float* __restrict__ b,
                                   const float* __restrict__ sw,
                                   const float* __restrict__ sb,
                                   const u64* __restrict__ uflag64,
                                   u64* __restrict__ opk64)
{
    int idx = blockIdx.x * blockDim.x + threadIdx.x;
    if (idx >= 128 * 482 * 4) return;
    u64 f = uflag64[idx];
    if (f == 0) return;
    int og = idx & 3;
    int lp = (idx >> 2) % 482;
    int n = idx / (4 * 482);
    u64 word = opk64[idx];
    const float* xb = x + (size_t)n * 3 * 2560;
    while (f) {
        int c = __ffsll(f) - 1;
        f &= f - 1;
        int co = og * 64 + c;
        const float* wp = w1 + (size_t)co * 69;
        double best = -1e300;
        for (int t = 0; t < 5; ++t) {
            int gl = 5 * lp - 2 + t;
            if (gl < 0 || gl >= 2406) continue;
            double s = 0.0;
            #pragma unroll
            for (int ci = 0; ci < 3; ++ci) {
                const float* xp = xb + ci * 2560 + gl;
                const float* wq = wp + ci * 23;
                #pragma unroll
                for (int kk = 0; kk < 23; ++kk) {
                    double xv = (double)xp[kk * 7];
                    s += (wq[kk] >= 0.0f) ? xv : -xv;
                }
            }
            best = fmax(best, s);
        }
        double v = ((sw[co] >= 0.0f) ? 0.1 : -0.1) * (0.1 * best + (double)b[co]) + (double)sb[co];
        u64 bit = (v >= 0.0) ? 1ull : 0ull;
        word = (word & ~(1ull << c)) | (bit << c);
    }
    opk64[idx] = word;
}

// -------------------- binary conv layers 2,3 (XNOR-popcount) ---------------
template<int K, int DIL, int PK, int PP, int W, int LPW>
__global__ void bconv_bit_kernel(const u64* __restrict__ apk,
                                 const u64* __restrict__ wpk,
                                 const float* __restrict__ b,
                                 const float* __restrict__ sw,
                                 const float* __restrict__ sb,
                                 u64* __restrict__ opk,
                                 int Cout, int Lin, int Lconv, int Lout,
                                 int NLPG, int nwaves)
{
    int wid = __builtin_amdgcn_readfirstlane(
        (int)(blockIdx.x * (blockDim.x >> 6)) + (int)(threadIdx.x >> 6));
    int lane = threadIdx.x & 63;
    if (wid >= nwaves) return;
    int WOUT = Cout >> 6;
    int og = wid % WOUT;
    int lpg = (wid / WOUT) % NLPG;
    int n  = wid / (WOUT * NLPG);
    int lp0 = lpg * LPW;
    int co = og * 64 + lane;

    const u64* ab = apk + (size_t)n * Lin * W;
    int cnt[LPW][PK];
    #pragma unroll
    for (int j = 0; j < LPW; ++j)
        #pragma unroll
        for (int t = 0; t < PK; ++t) cnt[j][t] = 0;

    #pragma unroll
    for (int k = 0; k < K; ++k) {
        u64 ww[W];
        #pragma unroll
        for (int w = 0; w < W; ++w)
            ww[w] = wpk[((size_t)k * Cout + co) * W + w];
        #pragma unroll
        for (int j = 0; j < LPW; ++j) {
            int lp = lp0 + j;
            #pragma unroll
            for (int t = 0; t < PK; ++t) {
                int l = lp * PK - PP + t;
                if (lp >= Lout || l < 0 || l >= Lconv) continue;
                const u64* ap = ab + (size_t)(l + k * DIL) * W;
                #pragma unroll
                for (int w = 0; w < W; ++w)
                    cnt[j][t] += __popcll(ap[w] ^ ww[w]);
            }
        }
    }
    const int CINK = W * 64 * K;
    #pragma unroll
    for (int j = 0; j < LPW; ++j) {
        int lp = lp0 + j;
        int best = -2147483647;
        #pragma unroll
        for (int t = 0; t < PK; ++t) {
            int l = lp * PK - PP + t;
            if (l < 0 || l >= Lconv) continue;
            int ksum = CINK - 2 * cnt[j][t];
            best = (ksum > best) ? ksum : best;
        }
        bool bit = false;
        if (lp < Lout) {
            double conv = 0.1 * (double)best + (double)b[co];
            double v = ((sw[co] >= 0.0f) ? 0.1 : -0.1) * conv + (double)sb[co];
            bit = (v >= 0.0);
        }
        u64 word = __ballot(bit);
        if (lp < Lout && lane == 0)
            opk[((size_t)n * Lout + lp) * WOUT + og] = word;
    }
}

// -------------------- fused tail: layers 4,5,6 + fc1 + fc2 -----------------
__global__ __launch_bounds__(256) void tail_kernel(
    const u64* __restrict__ a3,
    const u64* __restrict__ wpk4,
    const u64* __restrict__ wpk5,
    const u64* __restrict__ wpk6,
    const float* __restrict__ b4, const float* __restrict__ sw4, const float* __restrict__ sb4,
    const float* __restrict__ b5, const float* __restrict__ sw5, const float* __restrict__ sb5,
    const float* __restrict__ b6, const float* __restrict__ sw6, const float* __restrict__ sb6,
    const u32* __restrict__ fw1pk,
    const float* __restrict__ fsw1, const float* __restrict__ fsb1,
    const u64* __restrict__ fpk2,
    const float* __restrict__ fsw2, const float* __restrict__ fsb2,
    float* __restrict__ out)
{
    __shared__ u64 sA[46 * 4];
    __shared__ u64 sB[42 * 4];
    __shared__ u64 sC[13 * 4];
    __shared__ u32 sA6;
    __shared__ u64 sH[8];
    int n = blockIdx.x, tid = threadIdx.x, lane = tid & 63, wv = tid >> 6;

    for (int i = tid; i < 46 * 4; i += 256) sA[i] = a3[(size_t)n * 46 * 4 + i];
    __syncthreads();

    {
        u64 ww[5][4];
        #pragma unroll
        for (int k = 0; k < 5; ++k)
            #pragma unroll
            for (int w = 0; w < 4; ++w)
                ww[k][w] = wpk4[((size_t)k * 256 + tid) * 4 + w];
        double bc = b4[tid];
        double swc = (sw4[tid] >= 0.0f) ? 0.1 : -0.1;
        double sbc = sb4[tid];
        for (int lp = 0; lp < 42; ++lp) {
            int cnt = 0;
            #pragma unroll
            for (int k = 0; k < 5; ++k)
                #pragma unroll
                for (int w = 0; w < 4; ++w)
                    cnt += __popcll(sA[(lp + k) * 4 + w] ^ ww[k][w]);
            int ksum = 256 * 5 - 2 * cnt;
            double v = swc * (0.1 * ksum + bc) + sbc;
            u64 word = __ballot(v >= 0.0);
            if (lane == 0) sB[lp * 4 + wv] = word;
        }
    }
    __syncthreads();

    {
        u64 ww[5][4];
        #pragma unroll
        for (int k = 0; k < 5; ++k)
            #pragma unroll
            for (int w = 0; w < 4; ++w)
                ww[k][w] = wpk5[((size_t)k * 256 + tid) * 4 + w];
        double bc = b5[tid];
        double swc = (sw5[tid] >= 0.0f) ? 0.1 : -0.1;
        double sbc = sb5[tid];
        for (int lp = 0; lp < 13; ++lp) {
            int best = -2147483647;
            #pragma unroll
            for (int t = 0; t < 3; ++t) {
                int l = 3 * lp - 1 + t;
                if (l < 0 || l >= 38) continue;
                int cnt = 0;
                #pragma unroll
                for (int k = 0; k < 5; ++k)
                    #pragma unroll
                    for (int w = 0; w < 4; ++w)
                        cnt += __popcll(sB[(l + k) * 4 + w] ^ ww[k][w]);
                int ksum = 256 * 5 - 2 * cnt;
                best = (ksum > best) ? ksum : best;
            }
            double v = swc * (0.1 * best + bc) + sbc;
            u64 word = __ballot(v >= 0.0);
            if (lane == 0) sC[lp * 4 + wv] = word;
        }
    }
    __syncthreads();

    if (tid < 32) {
        int co = tid >> 2, lp = tid & 3;
        int best = -2147483647;
        for (int t = 0; t < 3; ++t) {
            int l = 3 * lp - 1 + t;
            if (l < 0 || l >= 11) continue;
            int cnt = 0;
            #pragma unroll
            for (int k = 0; k < 3; ++k)
                #pragma unroll
                for (int w = 0; w < 4; ++w)
                    cnt += __popcll(sC[(l + k) * 4 + w] ^ wpk6[((size_t)k * 8 + co) * 4 + w]);
            int ksum = 256 * 3 - 2 * cnt;
            best = (ksum > best) ? ksum : best;
        }
        double v = ((sw6[co] >= 0.0f) ? 0.1 : -0.1) * (0.1 * best + (double)b6[co]) + (double)sb6[co];
        u64 word = __ballot(v >= 0.0);
        if (tid == 0) sA6 = (u32)word;
    }
    __syncthreads();

    {
        u32 a6w = sA6;
        #pragma unroll
        for (int p = 0; p < 2; ++p) {
            int o = tid + p * 256;
            int k = 32 - 2 * __popc(a6w ^ fw1pk[o]);
            double v = ((fsw1[o] >= 0.0f) ? 0.1 : -0.1) * (0.1 * (double)k) + (double)fsb1[o];
            u64 word = __ballot(v >= 0.0);
            if (lane == 0) sH[p * 4 + wv] = word;
        }
    }
    __syncthreads();

    {
        u64 h[8];
        #pragma unroll
        for (int w = 0; w < 8; ++w) h[w] = sH[w];
        #pragma unroll
        for (int p = 0; p < 4; ++p) {
            int o = tid + p * 256;
            if (o < 1000) {
                int cnt = 0;
                #pragma unroll
                for (int w = 0; w < 8; ++w)
                    cnt += __popcll(h[w] ^ fpk2[(size_t)o * 8 + w]);
                int k = 512 - 2 * cnt;
                double v = ((fsw2[o] >= 0.0f) ? 0.1 : -0.1) * (0.1 * (double)k) + (double)fsb2[o];
                out[(size_t)n * 1000 + o] = (float)v;
            }
        }
    }
}

extern "C" void kernel_launch(void* const* d_in, const int* in_sizes, int n_in,
                              void* d_out, int out_size, void* d_ws, size_t ws_size,
                              hipStream_t stream) {
    const float* x = (const float*)d_in[0];
    const float *w[6], *b[6], *sw[6], *sb[6];
    for (int i = 0; i < 6; ++i) {
        w[i]  = (const float*)d_in[1 + 4 * i];
        b[i]  = (const float*)d_in[2 + 4 * i];
        sw[i] = (const float*)d_in[3 + 4 * i];
        sb[i] = (const float*)d_in[4 + 4 * i];
    }
    const float* fw1  = (const float*)d_in[25];
    const float* fsw1 = (const float*)d_in[26];
    const float* fsb1 = (const float*)d_in[27];
    const float* fw2  = (const float*)d_in[28];
    const float* fsw2 = (const float*)d_in[29];
    const float* fsb2 = (const float*)d_in[30];
    float* out = (float*)d_out;
    (void)in_sizes; (void)n_in; (void)out_size; (void)ws_size;

    char* wsbase = (char*)d_ws;
    size_t off = 0;
    auto alloc = [&](size_t bytes) -> char* {
        char* p = wsbase + off;
        off = (off + bytes + 255) & ~(size_t)255;
        return p;
    };
    u64* wpk2 = (u64*)alloc((size_t)13 * 256 * 4 * 8);
    u64* wpk3 = (u64*)alloc((size_t)7 * 256 * 4 * 8);
    u64* wpk4 = (u64*)alloc((size_t)5 * 256 * 4 * 8);
    u64* wpk5 = (u64*)alloc((size_t)5 * 256 * 4 * 8);
    u64* wpk6 = (u64*)alloc((size_t)3 * 8 * 4 * 8);
    u64* fpk2 = (u64*)alloc((size_t)1000 * 8 * 8);
    u32* fw1pk = (u32*)alloc((size_t)512 * 4);
    u16* wbf = (u16*)alloc((size_t)256 * 192 * 2);
    u64* uflag64 = (u64*)alloc((size_t)128 * 482 * 4 * 8);
    u64* a1   = (u64*)alloc((size_t)128 * 482 * 4 * 8);
    u64* a2   = (u64*)alloc((size_t)128 * 149 * 4 * 8);
    u64* a3   = (u64*)alloc((size_t)128 * 46 * 4 * 8);

    const int BLK = 256;
    auto blocksForWaves = [](int nwaves) { return dim3((unsigned)((nwaves * 64 + 255) / 256)); };
    auto blocksForThreads = [](int n) { return dim3((unsigned)((n + 255) / 256)); };

    // merged weight packing (+ misc tail: fc1 masks, layer-1 bf16 weights)
    {
        PackJobs P;
        int base = 0;
        auto setJob = [&](int i, const float* src, u64* dst, int Cout, int CIN, int K) {
            P.j[i] = {src, dst, Cout, CIN, K, base};
            base += K * Cout * (CIN >> 6);
        };
        setJob(0, w[1], wpk2, 256, 256, 13);
        setJob(1, w[2], wpk3, 256, 256, 7);
        setJob(2, w[3], wpk4, 256, 256, 5);
        setJob(3, w[4], wpk5, 256, 256, 5);
        setJob(4, w[5], wpk6, 8, 256, 3);
        setJob(5, fw2, fpk2, 1000, 512, 1);
        P.totalWaves = base;
        P.fw1 = fw1; P.fw1pk = fw1pk; P.w1 = w[0]; P.wbf = wbf;
        int totalThreads = base * 64 + 512 + 256 * 192;
        pack_all_kernel<<<blocksForThreads(totalThreads), BLK, 0, stream>>>(P);
    }

    // layer 1: split-bf16 MFMA GEMM + f64 fixup of near-zero outputs
    conv1_mfma_kernel<<<dim3(128, 31, 2), BLK, 0, stream>>>(
        x, wbf, b[0], sw[0], sb[0], a1, uflag64);
    conv1_fixup_kernel<<<blocksForThreads(128 * 482 * 4), BLK, 0, stream>>>(
        x, w[0], b[0], sw[0], sb[0], uflag64, a1);

    // layer 2: K=13 dil=3 pool(3,1): Lin=482 Lconv=446 Lout=149
    {
        const int NLPG = (149 + 3) / 4;
        int nw = 128 * NLPG * 4;
        bconv_bit_kernel<13, 3, 3, 1, 4, 4><<<blocksForWaves(nw), BLK, 0, stream>>>(
            a1, wpk2, b[1], sw[1], sb[1], a2, 256, 482, 446, 149, NLPG, nw);
    }
    // layer 3: K=7 dil=2 pool(3,1): Lin=149 Lconv=137 Lout=46
    {
        const int NLPG = (46 + 3) / 4;
        int nw = 128 * NLPG * 4;
        bconv_bit_kernel<7, 2, 3, 1, 4, 4><<<blocksForWaves(nw), BLK, 0, stream>>>(
            a2, wpk3, b[2], sw[2], sb[2], a3, 256, 149, 137, 46, NLPG, nw);
    }
    // fused tail: layers 4,5,6 + fc1 + fc2
    tail_kernel<<<dim3(128), BLK, 0, stream>>>(
        a3, wpk4, wpk5, wpk6,
        b[3], sw[3], sb[3], b[4], sw[4], sb[4], b[5], sw[5], sb[5],
        fw1pk, fsw1, fsb1, fpk2, fsw2, fsb2, out);
}

// Round 17
// 292.332 us; speedup vs baseline: 2.8410x; 1.0764x over previous
//
#include <hip/hip_runtime.h>
#include <cstdint>
#include <cstddef>

typedef unsigned long long u64;
typedef uint32_t u32;
typedef uint16_t u16;
typedef uint8_t u8;
typedef __attribute__((ext_vector_type(8))) short bf16x8;
typedef __attribute__((ext_vector_type(4))) float f32x4;

// ---------------------------------------------------------------------------
// Binary AlexNet-1D. bq(w)=0.1*sign(w), bact(x)=sign(x). All binary layers are
// exact integer XNOR-popcount + f64 affine epilogue. Activations bitpacked as
// [N][L][C/64] u64. Conv sum = CIN*K - 2*popc(a^w); maxpool (stride==kernel,
// scale 0.1>0) commutes with the affine map, so pool the integer sums.
// Layer 1 (real f32 input): bf16x2 split-precision MFMA GEMM (f32 sums exact
// to ~3e-6 << 1e-4 margin; near-zero outputs recomputed in f64 by fixup).
//   v3: co split 4-way per block (poolf 64 rows -> 30 KB LDS, ~5 blocks/CU).
// Binary convs: block-cooperative — activation rows staged to LDS once per
// block (kills 624 redundant wave-uniform VMEM issues per wave).
// Layers 4..6 + fc1 + fc2 fused into one block-per-sample kernel (LDS).
// ---------------------------------------------------------------------------

#define CONV1_MARGIN 1e-4f

// -------------------- merged weight packing --------------------
struct PackJob { const float* src; u64* dst; int Cout, CIN, K, waveBase; };
struct PackJobs {
    PackJob j[6]; int totalWaves;
    const float* fw1; u32* fw1pk;
    const float* w1;  u16* wbf;
};

__global__ void pack_all_kernel(PackJobs P)
{
    int gtid = blockIdx.x * blockDim.x + threadIdx.x;
    int wid = gtid >> 6, lane = gtid & 63;
    if (wid < P.totalWaves) {
        int jj = 0;
        #pragma unroll
        for (int i = 1; i < 6; ++i) if (wid >= P.j[i].waveBase) jj = i;
        PackJob job = P.j[jj];
        int lw = wid - job.waveBase;
        int W = job.CIN >> 6;
        int wg = lw % W;
        int co = (lw / W) % job.Cout;
        int k  = lw / (W * job.Cout);
        int ci = wg * 64 + lane;
        bool sg = job.src[((size_t)co * job.CIN + ci) * job.K + k] >= 0.0f;
        u64 word = __ballot(sg);
        if (lane == 0) job.dst[lw] = word;
        return;
    }
    int idx = gtid - P.totalWaves * 64;
    if (idx < 512) {
        u32 wd = 0;
        #pragma unroll
        for (int i = 0; i < 32; ++i) wd |= (u32)(P.fw1[idx * 32 + i] >= 0.0f) << i;
        P.fw1pk[idx] = wd;
    }
    int j = idx - 512;
    if (j >= 0 && j < 256 * 192) {
        int co = j / 192, k = j - co * 192;
        int i = (k >= 96) ? (k - 96) : k;
        u16 val = 0;
        if (i < 69)
            val = (P.w1[(size_t)co * 69 + i] >= 0.0f) ? (u16)0x3F80 : (u16)0xBF80;
        P.wbf[(size_t)co * 192 + k] = val;
    }
}

// -------------------- layer 1: split-bf16 MFMA GEMM (v3) --------------------
// grid (n=128, T=31 strips of 80 conv-pos = 16 lp, ch=4 co-quarters of 64),
// block 256 = 4 waves; each wave owns one 16-co tile.
__global__ __launch_bounds__(256) void conv1_mfma_kernel(
    const float* __restrict__ x, const u16* __restrict__ wbf,
    const float* __restrict__ b, const float* __restrict__ sw,
    const float* __restrict__ sb,
    u64* __restrict__ opk64, u64* __restrict__ uflag64)
{
    __shared__ u32 xhl[3 * 236];       // (lo<<16)|hi per x sample of the strip
    __shared__ u32 Xb32[16 * 108];     // [pos][k-pair]; hi dwords 0..47, lo 48..95
    __shared__ float poolf[64 * 81];   // [co_loc][q] raw conv sums
    const int Lconv = 2406, Lin = 2560;
    int n = blockIdx.x, T = blockIdx.y, ch = blockIdx.z;
    int tid = threadIdx.x, lane = tid & 63, w = tid >> 6;
    int l0 = 80 * T - 2;

    // A-frags (weights): one 16-co tile per wave
    bf16x8 afr[6];
    {
        int cobase = 64 * ch + 16 * w;
        const u16* wp = wbf + (size_t)(cobase + (lane & 15)) * 192 + (lane >> 4) * 8;
        #pragma unroll
        for (int s = 0; s < 6; ++s)
            afr[s] = *(const bf16x8*)(wp + s * 32);
    }

    // phase 0: convert strip's x to packed bf16 hi/lo, once
    const float* xb = x + (size_t)n * 3 * Lin;
    #pragma unroll
    for (int e = 0; e < 3; ++e) {
        int idx = tid + 256 * e;
        if (idx < 3 * 236) {
            int ci = idx / 236, lrel = idx - ci * 236;
            int l = min(max(l0 + lrel, 0), Lin - 1);   // clamp: only invalid
            float xv = xb[ci * Lin + l];               // conv positions read it
            u32 ub = __float_as_uint(xv);
            u32 h = (ub + 0x7FFFu + ((ub >> 16) & 1u)) >> 16;   // RNE bf16
            float rem = xv - __uint_as_float(h << 16);
            u32 ur = __float_as_uint(rem);
            u32 lo = (ur + 0x7FFFu + ((ur >> 16) & 1u)) >> 16;
            xhl[idx] = (h & 0xFFFFu) | (lo << 16);
        }
    }
    __syncthreads();

    for (int j = 0; j < 5; ++j) {
        if (j) __syncthreads();
        #pragma unroll
        for (int e = 0; e < 3; ++e) {
            int s = tid + 256 * e;           // 0..767
            int p = s & 15, i2 = s >> 4;     // taps 2i2, 2i2+1
            u32 hiw = 0, low = 0;
            #pragma unroll
            for (int t2 = 0; t2 < 2; ++t2) {
                int t = 2 * i2 + t2;
                if (t < 69) {
                    int ci = (t < 23) ? 0 : ((t < 46) ? 1 : 2);
                    int kk = t - 23 * ci;
                    u32 v = xhl[ci * 236 + 16 * j + p + 7 * kk];
                    hiw |= (v & 0xFFFFu) << (16 * t2);
                    low |= (v >> 16) << (16 * t2);
                }
            }
            Xb32[p * 108 + i2] = hiw;
            Xb32[p * 108 + 48 + i2] = low;
        }
        __syncthreads();

        f32x4 acc = {0.0f, 0.0f, 0.0f, 0.0f};
        const u16* brow = (const u16*)Xb32 + (lane & 15) * 216 + (lane >> 4) * 8;
        #pragma unroll
        for (int s = 0; s < 6; ++s) {
            bf16x8 bf = *(const bf16x8*)(brow + s * 32);
            acc = __builtin_amdgcn_mfma_f32_16x16x32_bf16(afr[s], bf, acc, 0, 0, 0);
        }

        int q = 16 * j + (lane & 15);
        #pragma unroll
        for (int r = 0; r < 4; ++r) {
            int co_loc = 16 * w + (lane >> 4) * 4 + r;
            poolf[co_loc * 81 + q] = acc[r];
        }
    }
    __syncthreads();

    // epilogue: guarded pool + affine + sign + ballot-pack
    #pragma unroll
    for (int it = 0; it < 4; ++it) {
        int idx = tid + 256 * it;        // 0..1023
        int co_loc = idx & 63;           // == lane
        int lp_loc = idx >> 6;           // 0..15 (wave-uniform)
        int lp = 16 * T + lp_loc;
        int co = 64 * ch + co_loc;
        bool bit = false, unc = false;
        if (lp < 482) {
            float best = -1e30f;
            #pragma unroll
            for (int t = 0; t < 5; ++t) {
                int q = 5 * lp_loc + t;
                int l = l0 + q;
                if (l >= 0 && l < Lconv)
                    best = fmaxf(best, poolf[co_loc * 81 + q]);
            }
            float v = ((sw[co] >= 0.0f) ? 0.1f : -0.1f) * (0.1f * best + b[co]) + sb[co];
            bit = (v >= 0.0f);
            unc = (fabsf(v) < CONV1_MARGIN);
        }
        u64 wb = __ballot(bit);
        u64 wu = __ballot(unc);
        if (lp < 482 && lane == 0) {
            size_t widx = ((size_t)n * 482 + lp) * 4 + ch;
            opk64[widx] = wb;
            uflag64[widx] = wu;
        }
    }
}

// Fixup: thread per packed u64 word; recompute flagged channels in f64.
__global__ void conv1_fixup_kernel(const float* __restrict__ x,
                                   const float* __restrict__ w1,
                                   const float* __restrict__ b,
                                   const float* __restrict__ sw,
                                   const float* __restrict__ sb,
                                   const u64* __restrict__ uflag64,
                                   u64* __restrict__ opk64)
{
    int idx = blockIdx.x * blockDim.x + threadIdx.x;
    if (idx >= 128 * 482 * 4) return;
    u64 f = uflag64[idx];
    if (f == 0) return;
    int og = idx & 3;
    int lp = (idx >> 2) % 482;
    int n = idx / (4 * 482);
    u64 word = opk64[idx];
    const float* xb = x + (size_t)n * 3 * 2560;
    while (f) {
        int c = __ffsll(f) - 1;
        f &= f - 1;
        int co = og * 64 + c;
        const float* wp = w1 + (size_t)co * 69;
        double best = -1e300;
        for (int t = 0; t < 5; ++t) {
            int gl = 5 * lp - 2 + t;
            if (gl < 0 || gl >= 2406) continue;
            double s = 0.0;
            #pragma unroll
            for (int ci = 0; ci < 3; ++ci) {
                const float* xp = xb + ci * 2560 + gl;
                const float* wq = wp + ci * 23;
                #pragma unroll
                for (int kk = 0; kk < 23; ++kk) {
                    double xv = (double)xp[kk * 7];
                    s += (wq[kk] >= 0.0f) ? xv : -xv;
                }
            }
            best = fmax(best, s);
        }
        double v = ((sw[co] >= 0.0f) ? 0.1 : -0.1) * (0.1 * best + (double)b[co]) + (double)sb[co];
        u64 bit = (v >= 0.0) ? 1ull : 0ull;
        word = (word & ~(1ull << c)) | (bit << c);
    }
    opk64[idx] = word;
}

// -------------- binary conv layers 2,3: block-cooperative LDS --------------
// block = (n, lp-group of LPW); 4 waves = 4 co-words. Activation rows staged
// into LDS once per block; popcount loop reads LDS broadcasts.
template<int K, int DIL, int PK, int PP, int W, int LPW>
__global__ __launch_bounds__(256) void bconv_lds_kernel(
    const u64* __restrict__ apk,  // [N][Lin][W]
    const u64* __restrict__ wpk,  // [K][Cout][W]
    const float* __restrict__ b,
    const float* __restrict__ sw,
    const float* __restrict__ sb,
    u64* __restrict__ opk,        // [N][Lout][Cout/64]
    int Cout, int Lin, int Lconv, int Lout)
{
    constexpr int SPAN = (LPW * PK - 1) + (K - 1) * DIL + 1;
    __shared__ u64 sAct[SPAN * W];
    int n = blockIdx.x, lpg = blockIdx.y;
    int tid = threadIdx.x, lane = tid & 63, og = tid >> 6;
    int lp0 = lpg * LPW;
    int lbase = lp0 * PK - PP;
    int WOUT = Cout >> 6;
    int co = og * 64 + lane;

    const u64* ab = apk + (size_t)n * Lin * W;
    for (int i = tid; i < SPAN * W; i += 256) {
        int li = lbase + i / W;
        sAct[i] = (li >= 0 && li < Lin) ? ab[(size_t)li * W + (i % W)] : 0ull;
    }
    __syncthreads();

    int cnt[LPW][PK];
    #pragma unroll
    for (int j = 0; j < LPW; ++j)
        #pragma unroll
        for (int t = 0; t < PK; ++t) cnt[j][t] = 0;

    #pragma unroll
    for (int k = 0; k < K; ++k) {
        u64 ww[W];
        #pragma unroll
        for (int w = 0; w < W; ++w)
            ww[w] = wpk[((size_t)k * Cout + co) * W + w];
        #pragma unroll
        for (int j = 0; j < LPW; ++j) {
            int lp = lp0 + j;
            #pragma unroll
            for (int t = 0; t < PK; ++t) {
                int l = lp * PK - PP + t;
                if (lp >= Lout || l < 0 || l >= Lconv) continue;
                const u64* ap = sAct + (size_t)(l + k * DIL - lbase) * W;
                #pragma unroll
                for (int w = 0; w < W; ++w)
                    cnt[j][t] += __popcll(ap[w] ^ ww[w]);
            }
        }
    }
    const int CINK = W * 64 * K;
    #pragma unroll
    for (int j = 0; j < LPW; ++j) {
        int lp = lp0 + j;
        int best = -2147483647;
        #pragma unroll
        for (int t = 0; t < PK; ++t) {
            int l = lp * PK - PP + t;
            if (l < 0 || l >= Lconv) continue;
            int ksum = CINK - 2 * cnt[j][t];
            best = (ksum > best) ? ksum : best;
        }
        bool bit = false;
        if (lp < Lout) {
            double conv = 0.1 * (double)best + (double)b[co];
            double v = ((sw[co] >= 0.0f) ? 0.1 : -0.1) * conv + (double)sb[co];
            bit = (v >= 0.0);
        }
        u64 word = __ballot(bit);
        if (lp < Lout && lane == 0)
            opk[((size_t)n * Lout + lp) * WOUT + og] = word;
    }
}

// -------------------- fused tail: layers 4,5,6 + fc1 + fc2 -----------------
__global__ __launch_bounds__(256) void tail_kernel(
    const u64* __restrict__ a3,
    const u64* __restrict__ wpk4,
    const u64* __restrict__ wpk5,
    const u64* __restrict__ wpk6,
    const float* __restrict__ b4, const float* __restrict__ sw4, const float* __restrict__ sb4,
    const float* __restrict__ b5, const float* __restrict__ sw5, const float* __restrict__ sb5,
    const float* __restrict__ b6, const float* __restrict__ sw6, const float* __restrict__ sb6,
    const u32* __restrict__ fw1pk,
    const float* __restrict__ fsw1, const float* __restrict__ fsb1,
    const u64* __restrict__ fpk2,
    const float* __restrict__ fsw2, const float* __restrict__ fsb2,
    float* __restrict__ out)
{
    __shared__ u64 sA[46 * 4];
    __shared__ u64 sB[42 * 4];
    __shared__ u64 sC[13 * 4];
    __shared__ u32 sA6;
    __shared__ u64 sH[8];
    int n = blockIdx.x, tid = threadIdx.x, lane = tid & 63, wv = tid >> 6;

    for (int i = tid; i < 46 * 4; i += 256) sA[i] = a3[(size_t)n * 46 * 4 + i];
    __syncthreads();

    {
        u64 ww[5][4];
        #pragma unroll
        for (int k = 0; k < 5; ++k)
            #pragma unroll
            for (int w = 0; w < 4; ++w)
                ww[k][w] = wpk4[((size_t)k * 256 + tid) * 4 + w];
        double bc = b4[tid];
        double swc = (sw4[tid] >= 0.0f) ? 0.1 : -0.1;
        double sbc = sb4[tid];
        for (int lp = 0; lp < 42; ++lp) {
            int cnt = 0;
            #pragma unroll
            for (int k = 0; k < 5; ++k)
                #pragma unroll
                for (int w = 0; w < 4; ++w)
                    cnt += __popcll(sA[(lp + k) * 4 + w] ^ ww[k][w]);
            int ksum = 256 * 5 - 2 * cnt;
            double v = swc * (0.1 * ksum + bc) + sbc;
            u64 word = __ballot(v >= 0.0);
            if (lane == 0) sB[lp * 4 + wv] = word;
        }
    }
    __syncthreads();

    {
        u64 ww[5][4];
        #pragma unroll
        for (int k = 0; k < 5; ++k)
            #pragma unroll
            for (int w = 0; w < 4; ++w)
                ww[k][w] = wpk5[((size_t)k * 256 + tid) * 4 + w];
        double bc = b5[tid];
        double swc = (sw5[tid] >= 0.0f) ? 0.1 : -0.1;
        double sbc = sb5[tid];
        for (int lp = 0; lp < 13; ++lp) {
            int best = -2147483647;
            #pragma unroll
            for (int t = 0; t < 3; ++t) {
                int l = 3 * lp - 1 + t;
                if (l < 0 || l >= 38) continue;
                int cnt = 0;
                #pragma unroll
                for (int k = 0; k < 5; ++k)
                    #pragma unroll
                    for (int w = 0; w < 4; ++w)
                        cnt += __popcll(sB[(l + k) * 4 + w] ^ ww[k][w]);
                int ksum = 256 * 5 - 2 * cnt;
                best = (ksum > best) ? ksum : best;
            }
            double v = swc * (0.1 * best + bc) + sbc;
            u64 word = __ballot(v >= 0.0);
            if (lane == 0) sC[lp * 4 + wv] = word;
        }
    }
    __syncthreads();

    if (tid < 32) {
        int co = tid >> 2, lp = tid & 3;
        int best = -2147483647;
        for (int t = 0; t < 3; ++t) {
            int l = 3 * lp - 1 + t;
            if (l < 0 || l >= 11) continue;
            int cnt = 0;
            #pragma unroll
            for (int k = 0; k < 3; ++k)
                #pragma unroll
                for (int w = 0; w < 4; ++w)
                    cnt += __popcll(sC[(l + k) * 4 + w] ^ wpk6[((size_t)k * 8 + co) * 4 + w]);
            int ksum = 256 * 3 - 2 * cnt;
            best = (ksum > best) ? ksum : best;
        }
        double v = ((sw6[co] >= 0.0f) ? 0.1 : -0.1) * (0.1 * best + (double)b6[co]) + (double)sb6[co];
        u64 word = __ballot(v >= 0.0);
        if (tid == 0) sA6 = (u32)word;
    }
    __syncthreads();

    {
        u32 a6w = sA6;
        #pragma unroll
        for (int p = 0; p < 2; ++p) {
            int o = tid + p * 256;
            int k = 32 - 2 * __popc(a6w ^ fw1pk[o]);
            double v = ((fsw1[o] >= 0.0f) ? 0.1 : -0.1) * (0.1 * (double)k) + (double)fsb1[o];
            u64 word = __ballot(v >= 0.0);
            if (lane == 0) sH[p * 4 + wv] = word;
        }
    }
    __syncthreads();

    {
        u64 h[8];
        #pragma unroll
        for (int w = 0; w < 8; ++w) h[w] = sH[w];
        #pragma unroll
        for (int p = 0; p < 4; ++p) {
            int o = tid + p * 256;
            if (o < 1000) {
                int cnt = 0;
                #pragma unroll
                for (int w = 0; w < 8; ++w)
                    cnt += __popcll(h[w] ^ fpk2[(size_t)o * 8 + w]);
                int k = 512 - 2 * cnt;
                double v = ((fsw2[o] >= 0.0f) ? 0.1 : -0.1) * (0.1 * (double)k) + (double)fsb2[o];
                out[(size_t)n * 1000 + o] = (float)v;
            }
        }
    }
}

extern "C" void kernel_launch(void* const* d_in, const int* in_sizes, int n_in,
                              void* d_out, int out_size, void* d_ws, size_t ws_size,
                              hipStream_t stream) {
    const float* x = (const float*)d_in[0];
    const float *w[6], *b[6], *sw[6], *sb[6];
    for (int i = 0; i < 6; ++i) {
        w[i]  = (const float*)d_in[1 + 4 * i];
        b[i]  = (const float*)d_in[2 + 4 * i];
        sw[i] = (const float*)d_in[3 + 4 * i];
        sb[i] = (const float*)d_in[4 + 4 * i];
    }
    const float* fw1  = (const float*)d_in[25];
    const float* fsw1 = (const float*)d_in[26];
    const float* fsb1 = (const float*)d_in[27];
    const float* fw2  = (const float*)d_in[28];
    const float* fsw2 = (const float*)d_in[29];
    const float* fsb2 = (const float*)d_in[30];
    float* out = (float*)d_out;
    (void)in_sizes; (void)n_in; (void)out_size; (void)ws_size;

    char* wsbase = (char*)d_ws;
    size_t off = 0;
    auto alloc = [&](size_t bytes) -> char* {
        char* p = wsbase + off;
        off = (off + bytes + 255) & ~(size_t)255;
        return p;
    };
    u64* wpk2 = (u64*)alloc((size_t)13 * 256 * 4 * 8);
    u64* wpk3 = (u64*)alloc((size_t)7 * 256 * 4 * 8);
    u64* wpk4 = (u64*)alloc((size_t)5 * 256 * 4 * 8);
    u64* wpk5 = (u64*)alloc((size_t)5 * 256 * 4 * 8);
    u64* wpk6 = (u64*)alloc((size_t)3 * 8 * 4 * 8);
    u64* fpk2 = (u64*)alloc((size_t)1000 * 8 * 8);
    u32* fw1pk = (u32*)alloc((size_t)512 * 4);
    u16* wbf = (u16*)alloc((size_t)256 * 192 * 2);
    u64* uflag64 = (u64*)alloc((size_t)128 * 482 * 4 * 8);
    u64* a1   = (u64*)alloc((size_t)128 * 482 * 4 * 8);
    u64* a2   = (u64*)alloc((size_t)128 * 149 * 4 * 8);
    u64* a3   = (u64*)alloc((size_t)128 * 46 * 4 * 8);

    const int BLK = 256;
    auto blocksForThreads = [](int n) { return dim3((unsigned)((n + 255) / 256)); };

    // merged weight packing (+ misc tail: fc1 masks, layer-1 bf16 weights)
    {
        PackJobs P;
        int base = 0;
        auto setJob = [&](int i, const float* src, u64* dst, int Cout, int CIN, int K) {
            P.j[i] = {src, dst, Cout, CIN, K, base};
            base += K * Cout * (CIN >> 6);
        };
        setJob(0, w[1], wpk2, 256, 256, 13);
        setJob(1, w[2], wpk3, 256, 256, 7);
        setJob(2, w[3], wpk4, 256, 256, 5);
        setJob(3, w[4], wpk5, 256, 256, 5);
        setJob(4, w[5], wpk6, 8, 256, 3);
        setJob(5, fw2, fpk2, 1000, 512, 1);
        P.totalWaves = base;
        P.fw1 = fw1; P.fw1pk = fw1pk; P.w1 = w[0]; P.wbf = wbf;
        int totalThreads = base * 64 + 512 + 256 * 192;
        pack_all_kernel<<<blocksForThreads(totalThreads), BLK, 0, stream>>>(P);
    }

    // layer 1: split-bf16 MFMA GEMM + f64 fixup of near-zero outputs
    conv1_mfma_kernel<<<dim3(128, 31, 4), BLK, 0, stream>>>(
        x, wbf, b[0], sw[0], sb[0], a1, uflag64);
    conv1_fixup_kernel<<<blocksForThreads(128 * 482 * 4), BLK, 0, stream>>>(
        x, w[0], b[0], sw[0], sb[0], uflag64, a1);

    // layer 2: K=13 dil=3 pool(3,1): Lin=482 Lconv=446 Lout=149
    bconv_lds_kernel<13, 3, 3, 1, 4, 4><<<dim3(128, (149 + 3) / 4), BLK, 0, stream>>>(
        a1, wpk2, b[1], sw[1], sb[1], a2, 256, 482, 446, 149);
    // layer 3: K=7 dil=2 pool(3,1): Lin=149 Lconv=137 Lout=46
    bconv_lds_kernel<7, 2, 3, 1, 4, 4><<<dim3(128, (46 + 3) / 4), BLK, 0, stream>>>(
        a2, wpk3, b[2], sw[2], sb[2], a3, 256, 149, 137, 46);
    // fused tail: layers 4,5,6 + fc1 + fc2
    tail_kernel<<<dim3(128), BLK, 0, stream>>>(
        a3, wpk4, wpk5, wpk6,
        b[3], sw[3], sb[3], b[4], sw[4], sb[4], b[5], sw[5], sb[5],
        fw1pk, fsw1, fsb1, fpk2, fsw2, fsb2, out);
}